// Round 10
// baseline (1704.867 us; speedup 1.0000x reference)
//
#include <hip/hip_runtime.h>

// ---------------------------------------------------------------------------
// DecoderBackbone: 4-layer llama-style decoder, B=2 T=1024 HID=2048,
// NH=16 NKV=4 HD=128, INTER=5632. fp32 residual stream, bf16 MFMA GEMMs.
// R10: gemm8d — back to 8-wave 128x64/wave geometry (R7, best measured), now
// with sub-K=32, 4x32KB LDS buffers and 3-deep counted-vmcnt prefetch
// (vmcnt(12)) to cover L3-latency staging. 16-wave structure abandoned
// (1/32 B/FLOP LDS ratio = at the 128 B/cyc CU budget -> structural cap).
// ---------------------------------------------------------------------------

typedef __attribute__((ext_vector_type(8))) __bf16 bf16x8;
typedef __attribute__((ext_vector_type(4))) float f32x4;
typedef __attribute__((ext_vector_type(4))) unsigned short u16x4;

#define DEV __device__ __forceinline__
#define BARRIER() asm volatile("s_barrier" ::: "memory")

#define NTOK 2048
#define HIDDIM 2048
#define KVDIM 512
#define HDIM 128
#define INTERDIM 5632

DEV unsigned short f2bf(float f) {
  union { float f; unsigned u; } a; a.f = f;
  unsigned r = a.u + 0x7fffu + ((a.u >> 16) & 1u);
  return (unsigned short)(r >> 16);
}
DEV float bf2f(unsigned short h) {
  union { unsigned u; float f; } a; a.u = ((unsigned)h) << 16;
  return a.f;
}
DEV unsigned short f2h(float f) {
  union { _Float16 h; unsigned short u; } c; c.h = (_Float16)f; return c.u;
}
DEV float h2f(unsigned short u) {
  union { unsigned short u; _Float16 h; } c; c.u = u; return (float)c.h;
}
DEV void gload_lds16(const void* g, void* l) {
  __builtin_amdgcn_global_load_lds(
      (const __attribute__((address_space(1))) unsigned int*)(g),
      (__attribute__((address_space(3))) unsigned int*)(l), 16, 0, 0);
}

// ---------------------------------------------------------------------------
__global__ __launch_bounds__(256) void cvt_kernel(
    const float* __restrict__ in, unsigned short* __restrict__ out, int n8) {
  const int i = blockIdx.x * 256 + threadIdx.x;
  if (i >= n8) return;
  const f32x4* p = reinterpret_cast<const f32x4*>(in) + (size_t)i * 2;
  const f32x4 a = p[0], b = p[1];
  bf16x8 o;
  o[0] = (__bf16)a.x; o[1] = (__bf16)a.y; o[2] = (__bf16)a.z; o[3] = (__bf16)a.w;
  o[4] = (__bf16)b.x; o[5] = (__bf16)b.y; o[6] = (__bf16)b.z; o[7] = (__bf16)b.w;
  *reinterpret_cast<bf16x8*>(out + (size_t)i * 8) = o;
}

// Interleaved gate/up convert: out[11264][2048], per 256-row group t:
// rows t*256..+127 = gate rows t*128.., rows +128.. = up rows t*128..
__global__ __launch_bounds__(256) void cvt_gu(
    const float* __restrict__ gw, const float* __restrict__ uw,
    unsigned short* __restrict__ out) {
  const int i = blockIdx.x * 256 + threadIdx.x;
  const int row = i >> 8, g8 = i & 255;
  const int t = row >> 8, sub = row & 255;
  const float* src = (sub < 128)
                         ? gw + (size_t)(t * 128 + sub) * 2048
                         : uw + (size_t)(t * 128 + sub - 128) * 2048;
  const f32x4* p = reinterpret_cast<const f32x4*>(src) + (size_t)g8 * 2;
  const f32x4 a = p[0], b = p[1];
  bf16x8 o;
  o[0] = (__bf16)a.x; o[1] = (__bf16)a.y; o[2] = (__bf16)a.z; o[3] = (__bf16)a.w;
  o[4] = (__bf16)b.x; o[5] = (__bf16)b.y; o[6] = (__bf16)b.z; o[7] = (__bf16)b.w;
  *reinterpret_cast<bf16x8*>(out + (size_t)row * 2048 + g8 * 8) = o;
}

// ---------------------------------------------------------------------------
template <int OUTF32>
__global__ __launch_bounds__(256) void rmsnorm_kernel(
    const float* __restrict__ x, const float* __restrict__ w,
    void* __restrict__ outp) {
  const int row = blockIdx.x, tid = threadIdx.x;
  const int lane = tid & 63, wave = tid >> 6;
  const float* xr = x + (size_t)row * HIDDIM;
  f32x4 v0 = *reinterpret_cast<const f32x4*>(xr + tid * 4);
  f32x4 v1 = *reinterpret_cast<const f32x4*>(xr + 1024 + tid * 4);
  float ss = v0.x * v0.x + v0.y * v0.y + v0.z * v0.z + v0.w * v0.w +
             v1.x * v1.x + v1.y * v1.y + v1.z * v1.z + v1.w * v1.w;
#pragma unroll
  for (int off = 1; off < 64; off <<= 1) ss += __shfl_xor(ss, off, 64);
  __shared__ float red[4];
  if (lane == 0) red[wave] = ss;
  __syncthreads();
  ss = red[0] + red[1] + red[2] + red[3];
  const float rs = rsqrtf(ss * (1.0f / 2048.0f) + 1e-6f);
  f32x4 w0 = *reinterpret_cast<const f32x4*>(w + tid * 4);
  f32x4 w1 = *reinterpret_cast<const f32x4*>(w + 1024 + tid * 4);
  if (OUTF32) {
    float* o = (float*)outp + (size_t)row * HIDDIM;
    f32x4 o0, o1;
    o0.x = v0.x * rs * w0.x; o0.y = v0.y * rs * w0.y;
    o0.z = v0.z * rs * w0.z; o0.w = v0.w * rs * w0.w;
    o1.x = v1.x * rs * w1.x; o1.y = v1.y * rs * w1.y;
    o1.z = v1.z * rs * w1.z; o1.w = v1.w * rs * w1.w;
    *reinterpret_cast<f32x4*>(o + tid * 4) = o0;
    *reinterpret_cast<f32x4*>(o + 1024 + tid * 4) = o1;
  } else {
    unsigned short* o = (unsigned short*)outp + (size_t)row * HIDDIM;
    u16x4 p0, p1;
    p0.x = f2bf(v0.x * rs * w0.x); p0.y = f2bf(v0.y * rs * w0.y);
    p0.z = f2bf(v0.z * rs * w0.z); p0.w = f2bf(v0.w * rs * w0.w);
    p1.x = f2bf(v1.x * rs * w1.x); p1.y = f2bf(v1.y * rs * w1.y);
    p1.z = f2bf(v1.z * rs * w1.z); p1.w = f2bf(v1.w * rs * w1.w);
    *reinterpret_cast<u16x4*>(o + tid * 4) = p0;
    *reinterpret_cast<u16x4*>(o + 1024 + tid * 4) = p1;
  }
}

// Fused split-K reduce + residual add + RMSNorm (bf16 partial planes).
template <int KS, int OUTF32>
__global__ __launch_bounds__(256) void reduce_rms(
    float* __restrict__ x, const unsigned short* __restrict__ p, size_t zs,
    const float* __restrict__ w, void* __restrict__ outp) {
  const int row = blockIdx.x, tid = threadIdx.x;
  const int lane = tid & 63, wave = tid >> 6;
  float* xr = x + (size_t)row * HIDDIM;
  f32x4 v0 = *reinterpret_cast<const f32x4*>(xr + tid * 4);
  f32x4 v1 = *reinterpret_cast<const f32x4*>(xr + 1024 + tid * 4);
#pragma unroll
  for (int s = 0; s < KS; ++s) {
    const unsigned short* pr = p + (size_t)s * zs + (size_t)row * HIDDIM;
    u16x4 a = *reinterpret_cast<const u16x4*>(pr + tid * 4);
    u16x4 b = *reinterpret_cast<const u16x4*>(pr + 1024 + tid * 4);
    v0.x += bf2f(a.x); v0.y += bf2f(a.y); v0.z += bf2f(a.z); v0.w += bf2f(a.w);
    v1.x += bf2f(b.x); v1.y += bf2f(b.y); v1.z += bf2f(b.z); v1.w += bf2f(b.w);
  }
  *reinterpret_cast<f32x4*>(xr + tid * 4) = v0;
  *reinterpret_cast<f32x4*>(xr + 1024 + tid * 4) = v1;
  float ss = v0.x * v0.x + v0.y * v0.y + v0.z * v0.z + v0.w * v0.w +
             v1.x * v1.x + v1.y * v1.y + v1.z * v1.z + v1.w * v1.w;
#pragma unroll
  for (int off = 1; off < 64; off <<= 1) ss += __shfl_xor(ss, off, 64);
  __shared__ float red[4];
  if (lane == 0) red[wave] = ss;
  __syncthreads();
  ss = red[0] + red[1] + red[2] + red[3];
  const float rs = rsqrtf(ss * (1.0f / 2048.0f) + 1e-6f);
  f32x4 w0 = *reinterpret_cast<const f32x4*>(w + tid * 4);
  f32x4 w1 = *reinterpret_cast<const f32x4*>(w + 1024 + tid * 4);
  if (OUTF32) {
    float* o = (float*)outp + (size_t)row * HIDDIM;
    f32x4 o0, o1;
    o0.x = v0.x * rs * w0.x; o0.y = v0.y * rs * w0.y;
    o0.z = v0.z * rs * w0.z; o0.w = v0.w * rs * w0.w;
    o1.x = v1.x * rs * w1.x; o1.y = v1.y * rs * w1.y;
    o1.z = v1.z * rs * w1.z; o1.w = v1.w * rs * w1.w;
    *reinterpret_cast<f32x4*>(o + tid * 4) = o0;
    *reinterpret_cast<f32x4*>(o + 1024 + tid * 4) = o1;
  } else {
    unsigned short* o = (unsigned short*)outp + (size_t)row * HIDDIM;
    u16x4 p0, p1;
    p0.x = f2bf(v0.x * rs * w0.x); p0.y = f2bf(v0.y * rs * w0.y);
    p0.z = f2bf(v0.z * rs * w0.z); p0.w = f2bf(v0.w * rs * w0.w);
    p1.x = f2bf(v1.x * rs * w1.x); p1.y = f2bf(v1.y * rs * w1.y);
    p1.z = f2bf(v1.z * rs * w1.z); p1.w = f2bf(v1.w * rs * w1.w);
    *reinterpret_cast<u16x4*>(o + tid * 4) = p0;
    *reinterpret_cast<u16x4*>(o + 1024 + tid * 4) = p1;
  }
}

// ---------------------------------------------------------------------------
// mfma16: one 16-MFMA cluster (4 mi x 4 ni) of an acc[8][4] wave tile.
// ---------------------------------------------------------------------------
template <int MB>
DEV void mfma16(const bf16x8 (&aF)[4], const bf16x8 (&bF)[4],
                f32x4 (&acc)[8][4]) {
#pragma unroll
  for (int ni = 0; ni < 4; ++ni)
#pragma unroll
    for (int mi = 0; mi < 4; ++mi)
      acc[MB + mi][ni] = __builtin_amdgcn_mfma_f32_16x16x32_bf16(
          aF[mi], bF[ni], acc[MB + mi][ni], 0, 0, 0);
}

// ---------------------------------------------------------------------------
// gemm8d: 256x256 tile, 8 waves (2M x 4N, 128x64/wave), sub-K=32,
// 4 x 32KB LDS buffers, 3-deep prefetch with counted vmcnt(12/8/4/0).
// Slot swizzle both sides (write: src col slot = (lane&3)^((lane>>3)&3) with
// linear LDS dest; read: slot = lq ^ ((fr>>1)&3); key=(row>>1)&3, row-base
// multiples of 16 keep it lane-local). C = A[M,K]*W[N,K]^T, bf16 partials out.
// kt_split/kt_tot in units of 32-K sub-tiles.
// ---------------------------------------------------------------------------
struct G8D {
  const unsigned short* src[4];
  int dstbase[4];   // element base in lds for buffer 0
};

DEV G8D g8d_setup(const unsigned short* A, const unsigned short* W, int K,
                  int m0, int n0, int t0, int wave, int lane) {
  G8D g;
  const int rl = lane >> 2;
  const int sl = ((lane & 3) ^ ((lane >> 3) & 3)) * 8;
#pragma unroll
  for (int j = 0; j < 4; ++j) {
    const int q0 = wave * 256 + j * 64;        // 16B-unit base of this load
    const int s = q0 >> 9;                     // section: 0,1=A 2,3=B
    const int r0 = (q0 & 511) >> 2;            // base row (multiple of 16)
    const unsigned short* mat =
        (s < 2) ? A + (size_t)(m0 + s * 128) * K
                : W + (size_t)(n0 + (s - 2) * 128) * K;
    g.src[j] = mat + (size_t)(r0 + rl) * K + sl + (size_t)t0 * 32;
    g.dstbase[j] = q0 * 8;
  }
  return g;
}

#define G8DSTAGE(g_, t_, c_)                                                  \
  do {                                                                        \
    _Pragma("unroll") for (int j = 0; j < 4; ++j)                             \
        gload_lds16(g_.src[j] + (size_t)(t_)*32,                              \
                    &lds[(c_)*16384 + g_.dstbase[j]]);                        \
  } while (0)

#define D8LDA(mi_, c_)                                                        \
  (*reinterpret_cast<const bf16x8*>(                                          \
      &lds[(c_)*16384 + wm * 4096 + ((mi_)*16 + fr) * 32 +                    \
           (lq ^ ((fr >> 1) & 3)) * 8]))
#define D8LDB(ni_, c_)                                                        \
  (*reinterpret_cast<const bf16x8*>(                                          \
      &lds[(c_)*16384 + (2 + (wn >> 1)) * 4096 +                              \
           ((wn & 1) * 64 + (ni_)*16 + fr) * 32 +                             \
           (lq ^ ((fr >> 1) & 3)) * 8]))

#define D8KLOOP(NS_)                                                          \
  if ((NS_) > 0) G8DSTAGE(g, 0, 0);                                           \
  if ((NS_) > 1) G8DSTAGE(g, 1, 1);                                           \
  if ((NS_) > 2) G8DSTAGE(g, 2, 2);                                           \
  for (int t = 0; t < (NS_); ++t) {                                           \
    const int c = t & 3;                                                      \
    if (t + 3 < (NS_)) G8DSTAGE(g, t + 3, (t + 3) & 3);                       \
    const int rem = (NS_)-1 - t;                                              \
    if (rem >= 3)                                                             \
      asm volatile("s_waitcnt vmcnt(12)" ::: "memory");                       \
    else if (rem == 2)                                                        \
      asm volatile("s_waitcnt vmcnt(8)" ::: "memory");                        \
    else if (rem == 1)                                                        \
      asm volatile("s_waitcnt vmcnt(4)" ::: "memory");                        \
    else                                                                      \
      asm volatile("s_waitcnt vmcnt(0)" ::: "memory");                        \
    BARRIER();                                                                \
    bF[0] = D8LDB(0, c); bF[1] = D8LDB(1, c);                                 \
    bF[2] = D8LDB(2, c); bF[3] = D8LDB(3, c);                                 \
    aF[0] = D8LDA(0, c); aF[1] = D8LDA(1, c);                                 \
    aF[2] = D8LDA(2, c); aF[3] = D8LDA(3, c);                                 \
    BARRIER();                                                                \
    __builtin_amdgcn_s_setprio(1);                                            \
    mfma16<0>(aF, bF, acc);                                                   \
    __builtin_amdgcn_s_setprio(0);                                            \
    __builtin_amdgcn_sched_barrier(0);                                        \
    BARRIER();                                                                \
    aF[0] = D8LDA(4, c); aF[1] = D8LDA(5, c);                                 \
    aF[2] = D8LDA(6, c); aF[3] = D8LDA(7, c);                                 \
    BARRIER();                                                                \
    __builtin_amdgcn_s_setprio(1);                                            \
    mfma16<4>(aF, bF, acc);                                                   \
    __builtin_amdgcn_s_setprio(0);                                            \
    __builtin_amdgcn_sched_barrier(0);                                        \
    BARRIER();                                                                \
  }

__global__ __launch_bounds__(512, 2) void gemm8d(
    const unsigned short* __restrict__ A, const unsigned short* __restrict__ W,
    unsigned short* __restrict__ outp, int K, int ldo, int kt_split,
    int kt_tot, size_t zstride) {
  __shared__ unsigned short lds[65536];   // 128 KB = 4 x 32 KB buffers
  const int tid = threadIdx.x, lane = tid & 63, wave = tid >> 6;
  const int fr = lane & 15, lq = lane >> 4;
  const int wm = wave >> 2, wn = wave & 3;

  int bx = blockIdx.x, by = blockIdx.y;
  {
    const int nbx = gridDim.x, nwg = nbx * gridDim.y;
    const int lin = by * nbx + bx, cpx = nwg >> 3;
    const int swz = (lin & 7) * cpx + (lin >> 3);
    bx = swz % nbx; by = swz / nbx;
  }
  const int m0 = by * 256, n0 = bx * 256;
  const int bz = blockIdx.z;
  const int t0 = bz * kt_split;
  int NS = kt_tot - t0; if (NS > kt_split) NS = kt_split;

  G8D g = g8d_setup(A, W, K, m0, n0, t0, wave, lane);
  f32x4 acc[8][4] = {};
  bf16x8 aF[4], bF[4];
  D8KLOOP(NS);

  const int r0 = lq * 4;
#pragma unroll
  for (int mi = 0; mi < 8; ++mi)
#pragma unroll
    for (int ni = 0; ni < 4; ++ni)
#pragma unroll
      for (int r = 0; r < 4; ++r) {
        const int gm = m0 + wm * 128 + mi * 16 + r0 + r;
        const int gn = n0 + wn * 64 + ni * 16 + fr;
        outp[(size_t)bz * zstride + (size_t)gm * ldo + gn] =
            f2bf(acc[mi][ni][r]);
      }
}

// GU variant: W = wgu[11264][2048] interleaved; epilogue exchanges gate
// values through LDS (f32, 128 KB) and stores silu(g)*u to act[2048][5632].
__global__ __launch_bounds__(512, 2) void gemm_gu8d(
    const unsigned short* __restrict__ A, const unsigned short* __restrict__ W,
    unsigned short* __restrict__ act) {
  __shared__ unsigned short lds[65536];
  const int tid = threadIdx.x, lane = tid & 63, wave = tid >> 6;
  const int fr = lane & 15, lq = lane >> 4;
  const int wm = wave >> 2, wn = wave & 3;
  const int K = 2048;

  int bx = blockIdx.x, by = blockIdx.y;
  {
    const int nbx = gridDim.x, nwg = nbx * gridDim.y;
    const int lin = by * nbx + bx, cpx = nwg >> 3;
    const int swz = (lin & 7) * cpx + (lin >> 3);
    bx = swz % nbx; by = swz / nbx;
  }
  const int m0 = by * 256, n0 = bx * 256;

  G8D g = g8d_setup(A, W, K, m0, n0, 0, wave, lane);
  f32x4 acc[8][4] = {};
  bf16x8 aF[4], bF[4];
  D8KLOOP(64);

  // epilogue: gate waves (wn<2) publish raw g via LDS f32; up waves (wn>=2)
  // compute silu(g)*u and store.
  float* fl = reinterpret_cast<float*>(lds);
  const int r0 = lq * 4;
  __syncthreads();
  if (wn < 2) {
#pragma unroll
    for (int mi = 0; mi < 8; ++mi)
#pragma unroll
      for (int ni = 0; ni < 4; ++ni)
#pragma unroll
        for (int r = 0; r < 4; ++r)
          fl[wm * 16384 + (mi * 16 + r0 + r) * 128 + wn * 64 + ni * 16 + fr] =
              acc[mi][ni][r];
  }
  __syncthreads();
  if (wn >= 2) {
    const int wnu = wn - 2;
#pragma unroll
    for (int mi = 0; mi < 8; ++mi)
#pragma unroll
      for (int ni = 0; ni < 4; ++ni)
#pragma unroll
        for (int r = 0; r < 4; ++r) {
          const int mrow = mi * 16 + r0 + r;
          const float gv = fl[wm * 16384 + mrow * 128 + wnu * 64 + ni * 16 + fr];
          const float s = gv / (1.f + __expf(-gv));
          const int gm = m0 + wm * 128 + mrow;
          const int ic = (n0 >> 1) + wnu * 64 + ni * 16 + fr;
          act[(size_t)gm * INTERDIM + ic] = f2bf(s * acc[mi][ni][r]);
        }
  }
}

// ---------------------------------------------------------------------------
// QK^T GEMM (8-wave, BK=64 structure): S = (Q.K^T)*scale, f16 out.
// ---------------------------------------------------------------------------
__global__ __launch_bounds__(512, 2) void gemm_qk(
    const unsigned short* __restrict__ q, const unsigned short* __restrict__ k,
    unsigned short* __restrict__ s) {
  __shared__ unsigned short lds[65536];
  const int tid = threadIdx.x, lane = tid & 63, wave = tid >> 6;
  const int fr = lane & 15, lq = lane >> 4;
  const int wm = wave >> 2, wn = wave & 3;

  int bx = blockIdx.x, by = blockIdx.y;
  {
    const int nbx = gridDim.x, nwg = nbx * gridDim.y;
    const int lin = by * nbx + bx, cpx = nwg >> 3;
    const int swz = (lin & 7) * cpx + (lin >> 3);
    bx = swz % nbx; by = swz / nbx;
  }
  if (bx > by) return;
  const int z = blockIdx.z, b = z >> 4, h = z & 15, kvh = h >> 2;
  const unsigned short* A = q + (size_t)b * 1024 * HIDDIM + h * HDIM;
  const unsigned short* W = k + (size_t)b * 1024 * KVDIM + kvh * HDIM;
  unsigned short* outp = s + (size_t)z * 1048576;
  const int m0 = by * 256, n0 = bx * 256;

  const int u0 = tid, u1 = tid + 512;
  const int r0s = u0 >> 3, r1s = u1 >> 3;
  const int c0 = ((u0 & 7) ^ (r0s & 7)) << 3, c1 = ((u1 & 7) ^ (r1s & 7)) << 3;
  const size_t offA0 = (size_t)r0s * HIDDIM + c0;
  const size_t offA1 = (size_t)r1s * HIDDIM + c1;
  const size_t offW0 = (size_t)r0s * KVDIM + c0;
  const size_t offW1 = (size_t)r1s * KVDIM + c1;
  const unsigned short* gb0 = A + (size_t)m0 * HIDDIM;
  const unsigned short* gb1 = A + (size_t)(m0 + 128) * HIDDIM;
  const unsigned short* gb2 = W + (size_t)n0 * KVDIM;
  const unsigned short* gb3 = W + (size_t)(n0 + 128) * KVDIM;

#define QSTAGE(h_, tt_, b_)                                                   \
  do {                                                                        \
    const unsigned short* _g =                                                \
        ((h_) == 0 ? gb0 : (h_) == 1 ? gb1 : (h_) == 2 ? gb2 : gb3) +         \
        (size_t)(tt_)*64;                                                     \
    const size_t _o0 = (h_) < 2 ? offA0 : offW0;                              \
    const size_t _o1 = (h_) < 2 ? offA1 : offW1;                              \
    unsigned short* _l = &lds[(b_)*32768 + (h_)*8192 + wave * 512];           \
    gload_lds16(_g + _o0, _l);                                                \
    gload_lds16(_g + _o1, _l + 4096);                                         \
  } while (0)

  const int e0 = lq ^ (fr & 7);
  const int cbA = wm * 8192;
  const int cbB = (2 + (wn >> 1)) * 8192;
  const int rB0 = (wn & 1) * 64 + fr;

#define QLDA(mi_, ks_, c_)                                                    \
  (*reinterpret_cast<const bf16x8*>(                                          \
      &lds[(c_)*32768 + cbA + ((mi_)*16 + fr) * 64 + ((e0 ^ ((ks_)*4)) << 3)]))
#define QLDB(ni_, ks_, c_)                                                    \
  (*reinterpret_cast<const bf16x8*>(                                          \
      &lds[(c_)*32768 + cbB + (rB0 + (ni_)*16) * 64 + ((e0 ^ ((ks_)*4)) << 3)]))

  f32x4 acc[8][4] = {};
  bf16x8 aF[4], bF[4];

  QSTAGE(0, 0, 0); QSTAGE(1, 0, 0); QSTAGE(2, 0, 0); QSTAGE(3, 0, 0);

  for (int t = 0; t < 2; ++t) {
    const int c = t & 1;
    if (t == 0) {
      QSTAGE(0, 1, 1); QSTAGE(2, 1, 1);
      asm volatile("s_waitcnt vmcnt(4)" ::: "memory");
    } else {
      asm volatile("s_waitcnt vmcnt(0)" ::: "memory");
    }
    BARRIER();
    bF[0] = QLDB(0, 0, c); bF[1] = QLDB(1, 0, c);
    bF[2] = QLDB(2, 0, c); bF[3] = QLDB(3, 0, c);
    aF[0] = QLDA(0, 0, c); aF[1] = QLDA(1, 0, c);
    aF[2] = QLDA(2, 0, c); aF[3] = QLDA(3, 0, c);
    if (t == 0) { QSTAGE(1, 1, 1); QSTAGE(3, 1, 1); }
    BARRIER();
    __builtin_amdgcn_s_setprio(1);
    mfma16<0>(aF, bF, acc);
    __builtin_amdgcn_s_setprio(0);
    __builtin_amdgcn_sched_barrier(0);
    BARRIER();
    aF[0] = QLDA(4, 0, c); aF[1] = QLDA(5, 0, c);
    aF[2] = QLDA(6, 0, c); aF[3] = QLDA(7, 0, c);
    BARRIER();
    __builtin_amdgcn_s_setprio(1);
    mfma16<4>(aF, bF, acc);
    __builtin_amdgcn_s_setprio(0);
    __builtin_amdgcn_sched_barrier(0);
    BARRIER();
    bF[0] = QLDB(0, 1, c); bF[1] = QLDB(1, 1, c);
    bF[2] = QLDB(2, 1, c); bF[3] = QLDB(3, 1, c);
    aF[0] = QLDA(0, 1, c); aF[1] = QLDA(1, 1, c);
    aF[2] = QLDA(2, 1, c); aF[3] = QLDA(3, 1, c);
    BARRIER();
    __builtin_amdgcn_s_setprio(1);
    mfma16<0>(aF, bF, acc);
    __builtin_amdgcn_s_setprio(0);
    __builtin_amdgcn_sched_barrier(0);
    BARRIER();
    aF[0] = QLDA(4, 1, c); aF[1] = QLDA(5, 1, c);
    aF[2] = QLDA(6, 1, c); aF[3] = QLDA(7, 1, c);
    BARRIER();
    __builtin_amdgcn_s_setprio(1);
    mfma16<4>(aF, bF, acc);
    __builtin_amdgcn_s_setprio(0);
    __builtin_amdgcn_sched_barrier(0);
    BARRIER();
  }

  const float scale = 0.08838834764831845f;
  const int r0 = lq * 4;
#pragma unroll
  for (int mi = 0; mi < 8; ++mi)
#pragma unroll
    for (int ni = 0; ni < 4; ++ni)
#pragma unroll
      for (int r = 0; r < 4; ++r) {
        const int gm = m0 + wm * 128 + mi * 16 + r0 + r;
        const int gn = n0 + wn * 64 + ni * 16 + fr;
        outp[(size_t)gm * 1024 + gn] = f2h(acc[mi][ni][r] * scale);
      }
#undef QSTAGE
#undef QLDA
#undef QLDB
}

// ---------------------------------------------------------------------------
__global__ __launch_bounds__(256) void softmax_rows(unsigned short* __restrict__ s) {
  const int row = blockIdx.x, tid = threadIdx.x;
  const int lane = tid & 63, wave = tid >> 6;
  const int qv = row & 1023;
  const int nact = ((qv >> 8) + 1) << 8;
  unsigned short* r = s + (size_t)row * 1024;
  const int col = tid * 4;
  const bool act = (col < nact);
  float v[4];
  if (act) {
    u16x4 raw = *reinterpret_cast<const u16x4*>(r + col);
#pragma unroll
    for (int j = 0; j < 4; ++j)
      v[j] = (col + j <= qv) ? h2f(((unsigned short*)&raw)[j]) : -1e30f;
  } else {
#pragma unroll
    for (int j = 0; j < 4; ++j) v[j] = -1e30f;
  }
  float mx = fmaxf(fmaxf(v[0], v[1]), fmaxf(v[2], v[3]));
#pragma unroll
  for (int off = 1; off < 64; off <<= 1) mx = fmaxf(mx, __shfl_xor(mx, off, 64));
  __shared__ float redm[4], reds[4];
  if (lane == 0) redm[wave] = mx;
  __syncthreads();
  const float M = fmaxf(fmaxf(redm[0], redm[1]), fmaxf(redm[2], redm[3]));
  float e[4], ts = 0.f;
#pragma unroll
  for (int j = 0; j < 4; ++j) {
    e[j] = (act && col + j <= qv) ? __expf(v[j] - M) : 0.f;
    ts += e[j];
  }
#pragma unroll
  for (int off = 1; off < 64; off <<= 1) ts += __shfl_xor(ts, off, 64);
  if (lane == 0) reds[wave] = ts;
  __syncthreads();
  const float inv = 1.f / (reds[0] + reds[1] + reds[2] + reds[3]);
  if (act) {
    u16x4 o;
    o.x = f2bf(e[0] * inv); o.y = f2bf(e[1] * inv);
    o.z = f2bf(e[2] * inv); o.w = f2bf(e[3] * inv);
    *reinterpret_cast<u16x4*>(r + col) = o;
  }
}

// ---------------------------------------------------------------------------
// PV GEMM: BM=256, BN=64, BK=64, 4 waves. NT = by*4+4. Grid (2,4,32).
// ---------------------------------------------------------------------------
__global__ __launch_bounds__(256, 2) void gemm_pv(
    const unsigned short* __restrict__ p, const unsigned short* __restrict__ vt,
    unsigned short* __restrict__ ao) {
  __shared__ unsigned short lds[40960];
  const int tid = threadIdx.x, lane = tid & 63, wave = tid >> 6;
  const int fr = lane & 15, lq = lane >> 4;
  const int bxn = blockIdx.x, by = blockIdx.y, z = blockIdx.z;
  const int b = z >> 4, h = z & 15, kvh = h >> 2;
  const int m0p = by * 256, n0 = bxn * 64;
  const int NT = by * 4 + 4;

  const unsigned short* A = p + (size_t)z * 1048576 + (size_t)m0p * 1024;
  const unsigned short* W =
      vt + ((size_t)(b * 4 + kvh) * 128 + n0) * 1024;

#define PVSTAGE(tt_, c_)                                                      \
  do {                                                                        \
    _Pragma("unroll")                                                         \
    for (int j = 0; j < 8; ++j) {                                             \
      const int u = wave * 512 + j * 64 + lane;                               \
      const int rw = u >> 3;                                                  \
      gload_lds16(A + (size_t)rw * 1024 + (((u & 7) ^ (rw & 7)) << 3) +       \
                      (size_t)(tt_)*64,                                       \
                  &lds[(c_)*20480 + wave * 4096 + j * 512]);                  \
    }                                                                         \
    _Pragma("unroll")                                                         \
    for (int j = 0; j < 2; ++j) {                                             \
      const int u = wave * 128 + j * 64 + lane;                               \
      const int rw = u >> 3;                                                  \
      gload_lds16(W + (size_t)rw * 1024 + (((u & 7) ^ (rw & 7)) << 3) +       \
                      (size_t)(tt_)*64,                                       \
                  &lds[(c_)*20480 + 16384 + wave * 1024 + j * 512]);          \
    }                                                                         \
  } while (0)

  const int e0 = lq ^ (fr & 7);
#define PVLDA(mi_, ks_, c_)                                                   \
  (*reinterpret_cast<const bf16x8*>(                                          \
      &lds[(c_)*20480 + (wave * 64 + (mi_)*16 + fr) * 64 +                    \
           ((e0 ^ ((ks_)*4)) << 3)]))
#define PVLDB(ni_, ks_, c_)                                                   \
  (*reinterpret_cast<const bf16x8*>(                                          \
      &lds[(c_)*20480 + 16384 + ((ni_)*16 + fr) * 64 +                        \
           ((e0 ^ ((ks_)*4)) << 3)]))

  f32x4 acc[4][4] = {};
  bf16x8 aF[4], bF[4];

  PVSTAGE(0, 0);

  for (int t = 0; t < NT; ++t) {
    const int c = t & 1;
    if (t + 1 < NT) {
      PVSTAGE(t + 1, c ^ 1);
      asm volatile("s_waitcnt vmcnt(10)" ::: "memory");
    } else {
      asm volatile("s_waitcnt vmcnt(0)" ::: "memory");
    }
    BARRIER();
#pragma unroll
    for (int ks = 0; ks < 2; ++ks) {
      bF[0] = PVLDB(0, ks, c); bF[1] = PVLDB(1, ks, c);
      bF[2] = PVLDB(2, ks, c); bF[3] = PVLDB(3, ks, c);
      aF[0] = PVLDA(0, ks, c); aF[1] = PVLDA(1, ks, c);
      aF[2] = PVLDA(2, ks, c); aF[3] = PVLDA(3, ks, c);
      BARRIER();
      __builtin_amdgcn_s_setprio(1);
#pragma unroll
      for (int ni = 0; ni < 4; ++ni)
#pragma unroll
        for (int mi = 0; mi < 4; ++mi)
          acc[mi][ni] = __builtin_amdgcn_mfma_f32_16x16x32_bf16(
              aF[mi], bF[ni], acc[mi][ni], 0, 0, 0);
      __builtin_amdgcn_s_setprio(0);
      __builtin_amdgcn_sched_barrier(0);
      BARRIER();
    }
  }

  const int r0 = lq * 4;
#pragma unroll
  for (int mi = 0; mi < 4; ++mi)
#pragma unroll
    for (int ni = 0; ni < 4; ++ni)
#pragma unroll
      for (int r = 0; r < 4; ++r) {
        const int gm = m0p + wave * 64 + mi * 16 + r0 + r;
        const int gn = n0 + ni * 16 + fr;
        ao[(size_t)(b * 1024 + gm) * HIDDIM + h * HDIM + gn] =
            f2bf(acc[mi][ni][r]);
      }
#undef PVSTAGE
#undef PVLDA
#undef PVLDB
}

// ---------------------------------------------------------------------------
// QKV split-K2 reduce (bf16 partials) + bias + RoPE + V-transpose.
// ---------------------------------------------------------------------------
__global__ __launch_bounds__(256) void reduce_qkv(
    const unsigned short* __restrict__ p, const float* __restrict__ qb,
    const float* __restrict__ kb, const float* __restrict__ vb,
    const float* __restrict__ cosb, const float* __restrict__ sinb,
    unsigned short* __restrict__ qo, unsigned short* __restrict__ ko,
    unsigned short* __restrict__ vto) {
  const int i = blockIdx.x * 256 + threadIdx.x;
  const int row = i / 768, c4 = (i - row * 768) * 4;
  const unsigned short* p0 = p + (size_t)row * 3072;
  const unsigned short* p1 = p + 6291456 + (size_t)row * 3072;
  const u16x4 a0 = *reinterpret_cast<const u16x4*>(p0 + c4);
  const u16x4 a1 = *reinterpret_cast<const u16x4*>(p1 + c4);
  f32x4 s;
  s.x = bf2f(a0.x) + bf2f(a1.x); s.y = bf2f(a0.y) + bf2f(a1.y);
  s.z = bf2f(a0.z) + bf2f(a1.z); s.w = bf2f(a0.w) + bf2f(a1.w);
  if (c4 < 2560) {
    const float* bias; unsigned short* out; int d, ldo;
    if (c4 < 2048) { bias = qb; out = qo; d = c4;        ldo = HIDDIM; }
    else           { bias = kb; out = ko; d = c4 - 2048; ldo = KVDIM; }
    const int dd = d & 127;
    const bool lohalf = (dd < 64);
    const int pc = lohalf ? c4 + 64 : c4 - 64;
    const int pd = lohalf ? d + 64 : d - 64;
    const u16x4 b0 = *reinterpret_cast<const u16x4*>(p0 + pc);
    const u16x4 b1 = *reinterpret_cast<const u16x4*>(p1 + pc);
    f32x4 sp;
    sp.x = bf2f(b0.x) + bf2f(b1.x); sp.y = bf2f(b0.y) + bf2f(b1.y);
    sp.z = bf2f(b0.z) + bf2f(b1.z); sp.w = bf2f(b0.w) + bf2f(b1.w);
    const f32x4 bv = *reinterpret_cast<const f32x4*>(bias + d);
    const f32x4 bp = *reinterpret_cast<const f32x4*>(bias + pd);
    const f32x4 cv = *reinterpret_cast<const f32x4*>(cosb + (size_t)row * 128 + dd);
    const f32x4 sv = *reinterpret_cast<const f32x4*>(sinb + (size_t)row * 128 + dd);
    const f32x4 xv = s + bv, pv = sp + bp;
    f32x4 o;
    if (lohalf) o = xv * cv - pv * sv;
    else        o = xv * cv + pv * sv;
    u16x4 ob;
    ob.x = f2bf(o.x); ob.y = f2bf(o.y); ob.z = f2bf(o.z); ob.w = f2bf(o.w);
    *reinterpret_cast<u16x4*>(out + (size_t)row * ldo + d) = ob;
  } else {
    const int d = c4 - 2560;
    const int kvh = d >> 7, dd = d & 127;
    const int b = row >> 10, t = row & 1023;
    const f32x4 bv = *reinterpret_cast<const f32x4*>(vb + d);
    const f32x4 o = s + bv;
    unsigned short* vr =
        vto + ((size_t)(b * 4 + kvh) * 128 + dd) * 1024 + t;
    vr[0] = f2bf(o.x); vr[1024] = f2bf(o.y);
    vr[2048] = f2bf(o.z); vr[3072] = f2bf(o.w);
  }
}

// ---------------------------------------------------------------------------
extern "C" void kernel_launch(void* const* d_in, const int* in_sizes, int n_in,
                              void* d_out, int out_size, void* d_ws,
                              size_t ws_size, hipStream_t stream) {
  (void)in_sizes; (void)n_in; (void)out_size; (void)ws_size;
  const float* hidden = (const float*)d_in[0];
  const float* cosb  = (const float*)d_in[1];
  const float* sinb  = (const float*)d_in[2];
  const float* qw    = (const float*)d_in[3];
  const float* qbias = (const float*)d_in[4];
  const float* kw    = (const float*)d_in[5];
  const float* kbias = (const float*)d_in[6];
  const float* vw    = (const float*)d_in[7];
  const float* vbias = (const float*)d_in[8];
  const float* ow    = (const float*)d_in[9];
  const float* gw    = (const float*)d_in[10];
  const float* uw    = (const float*)d_in[11];
  const float* dw    = (const float*)d_in[12];
  const float* ln1   = (const float*)d_in[13];
  const float* ln2   = (const float*)d_in[14];
  const float* normw = (const float*)d_in[15];

  char* ws = (char*)d_ws;
  float* x               = (float*)ws;                          // 0      16.8M
  unsigned short* hbuf   = (unsigned short*)(ws + 16777216);    // 16.8M   8.4M
  unsigned short* qbuf   = (unsigned short*)(ws + 25165824);    // 25.2M   8.4M
  unsigned short* kbuf   = (unsigned short*)(ws + 33554432);    // 33.6M   2.1M
  unsigned short* vtbuf  = (unsigned short*)(ws + 35651584);    // 35.7M   2.1M
  unsigned short* aobuf  = (unsigned short*)(ws + 39845888);    // 39.8M   8.4M
  unsigned short* actbuf = (unsigned short*)(ws + 71303168);    // 71.3M  23.1M
  unsigned short* wcvt   = (unsigned short*)(ws + 94371840);    // 94.4M  23.1M
  // Overlays (dead regions at time-of-use, stream-serialized):
  unsigned short* pbQKV = (unsigned short*)(ws + 37748736);  // 2x12.6MB
  unsigned short* sbuf  = (unsigned short*)(ws + 48234496);  // 67MB S/P planes
  unsigned short* pbO   = (unsigned short*)(ws + 48234496);  // 4x8.4MB
  unsigned short* wgu   = (unsigned short*)(ws + 25165824);  // 46.1MB
  unsigned short* pbD   = (unsigned short*)(ws + 25165824);  // 4x8.4MB

  unsigned short* wq16 = wcvt;
  unsigned short* wk16 = wcvt + 4194304;
  unsigned short* wv16 = wcvt + 5242880;
  unsigned short* ow16 = wcvt;

  hipMemcpyAsync(x, hidden, (size_t)NTOK * HIDDIM * 4,
                 hipMemcpyDeviceToDevice, stream);
  rmsnorm_kernel<0><<<NTOK, 256, 0, stream>>>(x, ln1, hbuf);

  for (int l = 0; l < 4; ++l) {
    const float* qw_l = qw + (size_t)l * 2048 * 2048;
    const float* qb_l = qbias + (size_t)l * 2048;
    const float* kw_l = kw + (size_t)l * 512 * 2048;
    const float* kb_l = kbias + (size_t)l * 512;
    const float* vw_l = vw + (size_t)l * 512 * 2048;
    const float* vb_l = vbias + (size_t)l * 512;
    const float* ow_l = ow + (size_t)l * 2048 * 2048;
    const float* gw_l = gw + (size_t)l * 5632 * 2048;
    const float* uw_l = uw + (size_t)l * 5632 * 2048;
    const float* dw_l = dw + (size_t)l * 2048 * 5632;

    cvt_kernel<<<2048, 256, 0, stream>>>(qw_l, wq16, 524288);
    cvt_kernel<<<512, 256, 0, stream>>>(kw_l, wk16, 131072);
    cvt_kernel<<<512, 256, 0, stream>>>(vw_l, wv16, 131072);
    // fused QKV: [2048,2048] x [3072,2048]^T, split-K2 (sub-K=32: 64 subtiles)
    gemm8d<<<dim3(12, 8, 2), 512, 0, stream>>>(
        hbuf, wcvt, pbQKV, 2048, 3072, 32, 64, (size_t)6291456);
    reduce_qkv<<<6144, 256, 0, stream>>>(pbQKV, qb_l, kb_l, vb_l, cosb, sinb,
                                         qbuf, kbuf, vtbuf);

    gemm_qk<<<dim3(4, 4, 32), 512, 0, stream>>>(qbuf, kbuf, sbuf);
    softmax_rows<<<32768, 256, 0, stream>>>(sbuf);
    gemm_pv<<<dim3(2, 4, 32), 256, 0, stream>>>(sbuf, vtbuf, aobuf);

    // O-proj: split-K4 (64 subtiles -> 16/split)
    cvt_kernel<<<2048, 256, 0, stream>>>(ow_l, ow16, 524288);
    gemm8d<<<dim3(8, 8, 4), 512, 0, stream>>>(
        aobuf, ow16, pbO, 2048, 2048, 16, 64, (size_t)4194304);
    reduce_rms<4, 0><<<NTOK, 256, 0, stream>>>(x, pbO, (size_t)4194304,
                                               ln2 + l * 2048, hbuf);

    // gate+up fused
    cvt_gu<<<11264, 256, 0, stream>>>(gw_l, uw_l, wgu);
    gemm_gu8d<<<dim3(44, 8), 512, 0, stream>>>(hbuf, wgu, actbuf);

    // down: split-K4 (K=5632 -> 176 subtiles -> 44/split)
    cvt_kernel<<<5632, 256, 0, stream>>>(dw_l, wcvt, 1441792);
    gemm8d<<<dim3(8, 8, 4), 512, 0, stream>>>(
        actbuf, wcvt, pbD, 5632, 2048, 44, 176, (size_t)4194304);
    if (l < 3) {
      reduce_rms<4, 0><<<NTOK, 256, 0, stream>>>(
          x, pbD, (size_t)4194304, ln1 + (l + 1) * 2048, hbuf);
    } else {
      reduce_rms<4, 1><<<NTOK, 256, 0, stream>>>(x, pbD, (size_t)4194304,
                                                 normw, d_out);
    }
  }
}

// Round 11
// 1619.239 us; speedup vs baseline: 1.0529x; 1.0529x over previous
//
#include <hip/hip_runtime.h>

// ---------------------------------------------------------------------------
// DecoderBackbone: 4-layer llama-style decoder, B=2 T=1024 HID=2048,
// NH=16 NKV=4 HD=128, INTER=5632. fp32 residual stream, bf16 MFMA GEMMs.
// R11: best-measured combo — gemm8p (8-wave BK=64 8-phase, R7) for GU;
// gemm16w (16-wave BK=32 swizzled, R9) for QKV/O/down — plus by-major XCD
// tile decode everywhere (each XCD keeps its W panels L2-resident instead of
// streaming the full W matrix: per-XCD L2-miss ~47MB -> ~14MB for GU).
// ---------------------------------------------------------------------------

typedef __attribute__((ext_vector_type(8))) __bf16 bf16x8;
typedef __attribute__((ext_vector_type(4))) float f32x4;
typedef __attribute__((ext_vector_type(4))) unsigned short u16x4;

#define DEV __device__ __forceinline__
#define BARRIER() asm volatile("s_barrier" ::: "memory")

#define NTOK 2048
#define HIDDIM 2048
#define KVDIM 512
#define HDIM 128
#define INTERDIM 5632

DEV unsigned short f2bf(float f) {
  union { float f; unsigned u; } a; a.f = f;
  unsigned r = a.u + 0x7fffu + ((a.u >> 16) & 1u);
  return (unsigned short)(r >> 16);
}
DEV float bf2f(unsigned short h) {
  union { unsigned u; float f; } a; a.u = ((unsigned)h) << 16;
  return a.f;
}
DEV unsigned short f2h(float f) {
  union { _Float16 h; unsigned short u; } c; c.h = (_Float16)f; return c.u;
}
DEV float h2f(unsigned short u) {
  union { unsigned short u; _Float16 h; } c; c.u = u; return (float)c.h;
}
DEV void gload_lds16(const void* g, void* l) {
  __builtin_amdgcn_global_load_lds(
      (const __attribute__((address_space(1))) unsigned int*)(g),
      (__attribute__((address_space(3))) unsigned int*)(l), 16, 0, 0);
}

// XCD-aware bijective decode, by-major within XCD chunk: XCD k's contiguous
// swz range cycles through ALL by (A panels) while touching few bx (W panels)
// -> W panels stay L2-resident per XCD.
DEV void xcd_decode(int& bx, int& by) {
  const int nbx = gridDim.x, nby = gridDim.y;
  const int nwg = nbx * nby;
  const int lin = by * nbx + bx, cpx = nwg >> 3;
  const int swz = (lin & 7) * cpx + (lin >> 3);
  by = swz % nby;
  bx = swz / nby;
}

// ---------------------------------------------------------------------------
__global__ __launch_bounds__(256) void cvt_kernel(
    const float* __restrict__ in, unsigned short* __restrict__ out, int n8) {
  const int i = blockIdx.x * 256 + threadIdx.x;
  if (i >= n8) return;
  const f32x4* p = reinterpret_cast<const f32x4*>(in) + (size_t)i * 2;
  const f32x4 a = p[0], b = p[1];
  bf16x8 o;
  o[0] = (__bf16)a.x; o[1] = (__bf16)a.y; o[2] = (__bf16)a.z; o[3] = (__bf16)a.w;
  o[4] = (__bf16)b.x; o[5] = (__bf16)b.y; o[6] = (__bf16)b.z; o[7] = (__bf16)b.w;
  *reinterpret_cast<bf16x8*>(out + (size_t)i * 8) = o;
}

// Interleaved gate/up convert: out[11264][2048], per 256-row group t:
// rows t*256..+127 = gate rows t*128.., rows +128.. = up rows t*128..
__global__ __launch_bounds__(256) void cvt_gu(
    const float* __restrict__ gw, const float* __restrict__ uw,
    unsigned short* __restrict__ out) {
  const int i = blockIdx.x * 256 + threadIdx.x;
  const int row = i >> 8, g8 = i & 255;
  const int t = row >> 8, sub = row & 255;
  const float* src = (sub < 128)
                         ? gw + (size_t)(t * 128 + sub) * 2048
                         : uw + (size_t)(t * 128 + sub - 128) * 2048;
  const f32x4* p = reinterpret_cast<const f32x4*>(src) + (size_t)g8 * 2;
  const f32x4 a = p[0], b = p[1];
  bf16x8 o;
  o[0] = (__bf16)a.x; o[1] = (__bf16)a.y; o[2] = (__bf16)a.z; o[3] = (__bf16)a.w;
  o[4] = (__bf16)b.x; o[5] = (__bf16)b.y; o[6] = (__bf16)b.z; o[7] = (__bf16)b.w;
  *reinterpret_cast<bf16x8*>(out + (size_t)row * 2048 + g8 * 8) = o;
}

// ---------------------------------------------------------------------------
template <int OUTF32>
__global__ __launch_bounds__(256) void rmsnorm_kernel(
    const float* __restrict__ x, const float* __restrict__ w,
    void* __restrict__ outp) {
  const int row = blockIdx.x, tid = threadIdx.x;
  const int lane = tid & 63, wave = tid >> 6;
  const float* xr = x + (size_t)row * HIDDIM;
  f32x4 v0 = *reinterpret_cast<const f32x4*>(xr + tid * 4);
  f32x4 v1 = *reinterpret_cast<const f32x4*>(xr + 1024 + tid * 4);
  float ss = v0.x * v0.x + v0.y * v0.y + v0.z * v0.z + v0.w * v0.w +
             v1.x * v1.x + v1.y * v1.y + v1.z * v1.z + v1.w * v1.w;
#pragma unroll
  for (int off = 1; off < 64; off <<= 1) ss += __shfl_xor(ss, off, 64);
  __shared__ float red[4];
  if (lane == 0) red[wave] = ss;
  __syncthreads();
  ss = red[0] + red[1] + red[2] + red[3];
  const float rs = rsqrtf(ss * (1.0f / 2048.0f) + 1e-6f);
  f32x4 w0 = *reinterpret_cast<const f32x4*>(w + tid * 4);
  f32x4 w1 = *reinterpret_cast<const f32x4*>(w + 1024 + tid * 4);
  if (OUTF32) {
    float* o = (float*)outp + (size_t)row * HIDDIM;
    f32x4 o0, o1;
    o0.x = v0.x * rs * w0.x; o0.y = v0.y * rs * w0.y;
    o0.z = v0.z * rs * w0.z; o0.w = v0.w * rs * w0.w;
    o1.x = v1.x * rs * w1.x; o1.y = v1.y * rs * w1.y;
    o1.z = v1.z * rs * w1.z; o1.w = v1.w * rs * w1.w;
    *reinterpret_cast<f32x4*>(o + tid * 4) = o0;
    *reinterpret_cast<f32x4*>(o + 1024 + tid * 4) = o1;
  } else {
    unsigned short* o = (unsigned short*)outp + (size_t)row * HIDDIM;
    u16x4 p0, p1;
    p0.x = f2bf(v0.x * rs * w0.x); p0.y = f2bf(v0.y * rs * w0.y);
    p0.z = f2bf(v0.z * rs * w0.z); p0.w = f2bf(v0.w * rs * w0.w);
    p1.x = f2bf(v1.x * rs * w1.x); p1.y = f2bf(v1.y * rs * w1.y);
    p1.z = f2bf(v1.z * rs * w1.z); p1.w = f2bf(v1.w * rs * w1.w);
    *reinterpret_cast<u16x4*>(o + tid * 4) = p0;
    *reinterpret_cast<u16x4*>(o + 1024 + tid * 4) = p1;
  }
}

// Fused split-K reduce + residual add + RMSNorm (bf16 partial planes).
template <int KS, int OUTF32>
__global__ __launch_bounds__(256) void reduce_rms(
    float* __restrict__ x, const unsigned short* __restrict__ p, size_t zs,
    const float* __restrict__ w, void* __restrict__ outp) {
  const int row = blockIdx.x, tid = threadIdx.x;
  const int lane = tid & 63, wave = tid >> 6;
  float* xr = x + (size_t)row * HIDDIM;
  f32x4 v0 = *reinterpret_cast<const f32x4*>(xr + tid * 4);
  f32x4 v1 = *reinterpret_cast<const f32x4*>(xr + 1024 + tid * 4);
#pragma unroll
  for (int s = 0; s < KS; ++s) {
    const unsigned short* pr = p + (size_t)s * zs + (size_t)row * HIDDIM;
    u16x4 a = *reinterpret_cast<const u16x4*>(pr + tid * 4);
    u16x4 b = *reinterpret_cast<const u16x4*>(pr + 1024 + tid * 4);
    v0.x += bf2f(a.x); v0.y += bf2f(a.y); v0.z += bf2f(a.z); v0.w += bf2f(a.w);
    v1.x += bf2f(b.x); v1.y += bf2f(b.y); v1.z += bf2f(b.z); v1.w += bf2f(b.w);
  }
  *reinterpret_cast<f32x4*>(xr + tid * 4) = v0;
  *reinterpret_cast<f32x4*>(xr + 1024 + tid * 4) = v1;
  float ss = v0.x * v0.x + v0.y * v0.y + v0.z * v0.z + v0.w * v0.w +
             v1.x * v1.x + v1.y * v1.y + v1.z * v1.z + v1.w * v1.w;
#pragma unroll
  for (int off = 1; off < 64; off <<= 1) ss += __shfl_xor(ss, off, 64);
  __shared__ float red[4];
  if (lane == 0) red[wave] = ss;
  __syncthreads();
  ss = red[0] + red[1] + red[2] + red[3];
  const float rs = rsqrtf(ss * (1.0f / 2048.0f) + 1e-6f);
  f32x4 w0 = *reinterpret_cast<const f32x4*>(w + tid * 4);
  f32x4 w1 = *reinterpret_cast<const f32x4*>(w + 1024 + tid * 4);
  if (OUTF32) {
    float* o = (float*)outp + (size_t)row * HIDDIM;
    f32x4 o0, o1;
    o0.x = v0.x * rs * w0.x; o0.y = v0.y * rs * w0.y;
    o0.z = v0.z * rs * w0.z; o0.w = v0.w * rs * w0.w;
    o1.x = v1.x * rs * w1.x; o1.y = v1.y * rs * w1.y;
    o1.z = v1.z * rs * w1.z; o1.w = v1.w * rs * w1.w;
    *reinterpret_cast<f32x4*>(o + tid * 4) = o0;
    *reinterpret_cast<f32x4*>(o + 1024 + tid * 4) = o1;
  } else {
    unsigned short* o = (unsigned short*)outp + (size_t)row * HIDDIM;
    u16x4 p0, p1;
    p0.x = f2bf(v0.x * rs * w0.x); p0.y = f2bf(v0.y * rs * w0.y);
    p0.z = f2bf(v0.z * rs * w0.z); p0.w = f2bf(v0.w * rs * w0.w);
    p1.x = f2bf(v1.x * rs * w1.x); p1.y = f2bf(v1.y * rs * w1.y);
    p1.z = f2bf(v1.z * rs * w1.z); p1.w = f2bf(v1.w * rs * w1.w);
    *reinterpret_cast<u16x4*>(o + tid * 4) = p0;
    *reinterpret_cast<u16x4*>(o + 1024 + tid * 4) = p1;
  }
}

// ---------------------------------------------------------------------------
// mfma16: one 16-MFMA cluster of an acc[8][4] wave tile (8-wave kernels).
// ---------------------------------------------------------------------------
template <int MB>
DEV void mfma16(const bf16x8 (&aF)[4], const bf16x8 (&bF)[4],
                f32x4 (&acc)[8][4]) {
#pragma unroll
  for (int ni = 0; ni < 4; ++ni)
#pragma unroll
    for (int mi = 0; mi < 4; ++mi)
      acc[MB + mi][ni] = __builtin_amdgcn_mfma_f32_16x16x32_bf16(
          aF[mi], bF[ni], acc[MB + mi][ni], 0, 0, 0);
}

// ---------------------------------------------------------------------------
// gemm16w (R9): 256x256 tile, 16 waves (4Mx4N, 64x64/wave), BK=32, 64KB LDS
// dbuf, counted vmcnt(2), XOR slot swizzle both sides. bf16 partial planes.
// ---------------------------------------------------------------------------
struct G16Setup {
  const unsigned short* srcp0;
  const unsigned short* srcp1;
  int ldsc0, ldsc1;
};

DEV G16Setup g16_setup(const unsigned short* A, const unsigned short* W,
                       int K, int m0, int n0, int t0, int wave, int lane) {
  const int c0 = wave * 2, c1 = wave * 2 + 1;
  const int rA = lane >> 2;
  const int cg = (((lane & 3) ^ ((lane >> 3) & 3))) * 8;   // swizzled src slot
  G16Setup s;
  const unsigned short* gb[4] = {
      A + (size_t)m0 * K, A + (size_t)(m0 + 128) * K,
      W + (size_t)n0 * K, W + (size_t)(n0 + 128) * K};
  s.srcp0 = gb[c0 >> 3] + (size_t)((c0 & 7) * 16 + rA) * K + cg +
            (size_t)t0 * 32;
  s.srcp1 = gb[c1 >> 3] + (size_t)((c1 & 7) * 16 + rA) * K + cg +
            (size_t)t0 * 32;
  s.ldsc0 = c0 * 512;
  s.ldsc1 = c1 * 512;
  return s;
}

#define G16STAGE(st_, tt_, c_)                                                \
  do {                                                                        \
    gload_lds16(st_.srcp0 + (size_t)(tt_)*32, &lds[(c_)*16384 + st_.ldsc0]);  \
    gload_lds16(st_.srcp1 + (size_t)(tt_)*32, &lds[(c_)*16384 + st_.ldsc1]);  \
  } while (0)

#define G16LDA(mi_, c_)                                                       \
  (*reinterpret_cast<const bf16x8*>(                                          \
      &lds[(c_)*16384 + (wm >> 1) * 4096 +                                    \
           (((wm & 1) * 64) + (mi_)*16 + fr) * 32 +                           \
           ((lq ^ ((fr >> 1) & 3))) * 8]))
#define G16LDB(ni_, c_)                                                       \
  (*reinterpret_cast<const bf16x8*>(                                          \
      &lds[(c_)*16384 + (2 + (wn >> 1)) * 4096 +                              \
           (((wn & 1) * 64) + (ni_)*16 + fr) * 32 +                           \
           ((lq ^ ((fr >> 1) & 3))) * 8]))

#define G16KLOOP(NT_)                                                         \
  G16STAGE(st, 0, 0);                                                         \
  for (int t = 0; t < (NT_); ++t) {                                           \
    const int c = t & 1;                                                      \
    if (t + 1 < (NT_)) {                                                      \
      G16STAGE(st, t + 1, c ^ 1);                                             \
      asm volatile("s_waitcnt vmcnt(2)" ::: "memory");                        \
    } else {                                                                  \
      asm volatile("s_waitcnt vmcnt(0)" ::: "memory");                        \
    }                                                                         \
    BARRIER();                                                                \
    bf16x8 aF[4], bF[4];                                                      \
    bF[0] = G16LDB(0, c); bF[1] = G16LDB(1, c);                               \
    bF[2] = G16LDB(2, c); bF[3] = G16LDB(3, c);                               \
    aF[0] = G16LDA(0, c); aF[1] = G16LDA(1, c);                               \
    aF[2] = G16LDA(2, c); aF[3] = G16LDA(3, c);                               \
    __builtin_amdgcn_s_setprio(1);                                            \
    _Pragma("unroll") for (int ni = 0; ni < 4; ++ni)                          \
        _Pragma("unroll") for (int mi = 0; mi < 4; ++mi)                      \
            acc[mi][ni] = __builtin_amdgcn_mfma_f32_16x16x32_bf16(            \
                aF[mi], bF[ni], acc[mi][ni], 0, 0, 0);                        \
    __builtin_amdgcn_s_setprio(0);                                            \
    __builtin_amdgcn_sched_barrier(0);                                        \
    BARRIER();                                                                \
  }

__global__ __launch_bounds__(1024) void gemm16w(
    const unsigned short* __restrict__ A, const unsigned short* __restrict__ W,
    unsigned short* __restrict__ outp, int K, int ldo, int kt_split,
    int kt_tot, size_t zstride) {
  __shared__ unsigned short lds[32768];   // 64 KB
  const int tid = threadIdx.x, lane = tid & 63, wave = tid >> 6;
  const int fr = lane & 15, lq = lane >> 4;
  const int wm = wave >> 2, wn = wave & 3;

  int bx = blockIdx.x, by = blockIdx.y;
  xcd_decode(bx, by);
  const int m0 = by * 256, n0 = bx * 256;
  const int bz = blockIdx.z;
  const int t0 = bz * kt_split;
  int NT = kt_tot - t0; if (NT > kt_split) NT = kt_split;

  G16Setup st = g16_setup(A, W, K, m0, n0, t0, wave, lane);
  f32x4 acc[4][4] = {};
  G16KLOOP(NT);

  const int r0 = lq * 4;
#pragma unroll
  for (int mi = 0; mi < 4; ++mi)
#pragma unroll
    for (int ni = 0; ni < 4; ++ni)
#pragma unroll
      for (int r = 0; r < 4; ++r) {
        const int gm = m0 + wm * 64 + mi * 16 + r0 + r;
        const int gn = n0 + wn * 64 + ni * 16 + fr;
        outp[(size_t)bz * zstride + (size_t)gm * ldo + gn] =
            f2bf(acc[mi][ni][r]);
      }
}

// ---------------------------------------------------------------------------
// gemm_gu (R7 8-wave BK=64 8-phase): W = wgu[11264][2048] interleaved;
// epilogue exchanges gate values through LDS (f32) and stores silu(g)*u.
// ---------------------------------------------------------------------------
__global__ __launch_bounds__(512, 2) void gemm_gu(
    const unsigned short* __restrict__ A, const unsigned short* __restrict__ W,
    unsigned short* __restrict__ act) {
  __shared__ unsigned short lds[65536];
  const int tid = threadIdx.x, lane = tid & 63, wave = tid >> 6;
  const int fr = lane & 15, lq = lane >> 4;
  const int wm = wave >> 2, wn = wave & 3;
  const int K = 2048;

  int bx = blockIdx.x, by = blockIdx.y;
  xcd_decode(bx, by);
  const int m0 = by * 256, n0 = bx * 256;

  const int u0 = tid, u1 = tid + 512;
  const int r0s = u0 >> 3, r1s = u1 >> 3;
  const size_t off0 = (size_t)r0s * K + (size_t)((((u0 & 7) ^ (r0s & 7))) << 3);
  const size_t off1 = (size_t)r1s * K + (size_t)((((u1 & 7) ^ (r1s & 7))) << 3);
  const unsigned short* gb0 = A + (size_t)(m0)*K;
  const unsigned short* gb1 = A + (size_t)(m0 + 128) * K;
  const unsigned short* gb2 = W + (size_t)(n0)*K;
  const unsigned short* gb3 = W + (size_t)(n0 + 128) * K;

#define STAGE(h_, tt_, b_)                                                    \
  do {                                                                        \
    const unsigned short* _g =                                                \
        ((h_) == 0 ? gb0 : (h_) == 1 ? gb1 : (h_) == 2 ? gb2 : gb3) +         \
        (size_t)(tt_)*64;                                                     \
    unsigned short* _l = &lds[(b_)*32768 + (h_)*8192 + wave * 512];           \
    gload_lds16(_g + off0, _l);                                               \
    gload_lds16(_g + off1, _l + 4096);                                        \
  } while (0)

  const int e0 = lq ^ (fr & 7);
  const int cbA = wm * 8192;
  const int cbB = (2 + (wn >> 1)) * 8192;
  const int rB0 = (wn & 1) * 64 + fr;

#define LDA(mi_, ks_, c_)                                                     \
  (*reinterpret_cast<const bf16x8*>(                                          \
      &lds[(c_)*32768 + cbA + ((mi_)*16 + fr) * 64 + ((e0 ^ ((ks_)*4)) << 3)]))
#define LDB(ni_, ks_, c_)                                                     \
  (*reinterpret_cast<const bf16x8*>(                                          \
      &lds[(c_)*32768 + cbB + (rB0 + (ni_)*16) * 64 + ((e0 ^ ((ks_)*4)) << 3)]))

  f32x4 acc[8][4] = {};
  bf16x8 aF[4], bF[4];

  STAGE(0, 0, 0); STAGE(1, 0, 0); STAGE(2, 0, 0); STAGE(3, 0, 0);

  for (int t = 0; t < 32; ++t) {
    const int c = t & 1;
    if (t + 1 < 32) {
      STAGE(0, t + 1, c ^ 1);
      STAGE(2, t + 1, c ^ 1);
      asm volatile("s_waitcnt vmcnt(4)" ::: "memory");
    } else {
      asm volatile("s_waitcnt vmcnt(0)" ::: "memory");
    }
    BARRIER();
    bF[0] = LDB(0, 0, c); bF[1] = LDB(1, 0, c);
    bF[2] = LDB(2, 0, c); bF[3] = LDB(3, 0, c);
    aF[0] = LDA(0, 0, c); aF[1] = LDA(1, 0, c);
    aF[2] = LDA(2, 0, c); aF[3] = LDA(3, 0, c);
    if (t + 1 < 32) { STAGE(1, t + 1, c ^ 1); STAGE(3, t + 1, c ^ 1); }
    BARRIER();
    __builtin_amdgcn_s_setprio(1);
    mfma16<0>(aF, bF, acc);
    __builtin_amdgcn_s_setprio(0);
    __builtin_amdgcn_sched_barrier(0);
    BARRIER();
    aF[0] = LDA(4, 0, c); aF[1] = LDA(5, 0, c);
    aF[2] = LDA(6, 0, c); aF[3] = LDA(7, 0, c);
    BARRIER();
    __builtin_amdgcn_s_setprio(1);
    mfma16<4>(aF, bF, acc);
    __builtin_amdgcn_s_setprio(0);
    __builtin_amdgcn_sched_barrier(0);
    BARRIER();
    bF[0] = LDB(0, 1, c); bF[1] = LDB(1, 1, c);
    bF[2] = LDB(2, 1, c); bF[3] = LDB(3, 1, c);
    aF[0] = LDA(0, 1, c); aF[1] = LDA(1, 1, c);
    aF[2] = LDA(2, 1, c); aF[3] = LDA(3, 1, c);
    BARRIER();
    __builtin_amdgcn_s_setprio(1);
    mfma16<0>(aF, bF, acc);
    __builtin_amdgcn_s_setprio(0);
    __builtin_amdgcn_sched_barrier(0);
    BARRIER();
    aF[0] = LDA(4, 1, c); aF[1] = LDA(5, 1, c);
    aF[2] = LDA(6, 1, c); aF[3] = LDA(7, 1, c);
    BARRIER();
    __builtin_amdgcn_s_setprio(1);
    mfma16<4>(aF, bF, acc);
    __builtin_amdgcn_s_setprio(0);
    __builtin_amdgcn_sched_barrier(0);
    BARRIER();
  }

  // epilogue: exchange gate values through LDS (f32 view, 32768 floats)
  float* fl = reinterpret_cast<float*>(lds);
  const int r0 = lq * 4;
  __syncthreads();
  if (wn < 2) {
#pragma unroll
    for (int mi = 0; mi < 8; ++mi)
#pragma unroll
      for (int ni = 0; ni < 4; ++ni)
#pragma unroll
        for (int r = 0; r < 4; ++r)
          fl[wm * 16384 + (mi * 16 + r0 + r) * 128 + wn * 64 + ni * 16 + fr] =
              acc[mi][ni][r];
  }
  __syncthreads();
  if (wn >= 2) {
    const int wnu = wn - 2;
#pragma unroll
    for (int mi = 0; mi < 8; ++mi)
#pragma unroll
      for (int ni = 0; ni < 4; ++ni)
#pragma unroll
        for (int r = 0; r < 4; ++r) {
          const int mrow = mi * 16 + r0 + r;
          const float gv = fl[wm * 16384 + mrow * 128 + wnu * 64 + ni * 16 + fr];
          const float s = gv / (1.f + __expf(-gv));
          const int gm = m0 + wm * 128 + mrow;
          const int ic = (n0 >> 1) + wnu * 64 + ni * 16 + fr;
          act[(size_t)gm * INTERDIM + ic] = f2bf(s * acc[mi][ni][r]);
        }
  }
#undef STAGE
#undef LDA
#undef LDB
}

// ---------------------------------------------------------------------------
// QK^T GEMM (8-wave, BK=64 structure): S = (Q.K^T)*scale, f16 out.
// ---------------------------------------------------------------------------
__global__ __launch_bounds__(512, 2) void gemm_qk(
    const unsigned short* __restrict__ q, const unsigned short* __restrict__ k,
    unsigned short* __restrict__ s) {
  __shared__ unsigned short lds[65536];
  const int tid = threadIdx.x, lane = tid & 63, wave = tid >> 6;
  const int fr = lane & 15, lq = lane >> 4;
  const int wm = wave >> 2, wn = wave & 3;

  int bx = blockIdx.x, by = blockIdx.y;
  xcd_decode(bx, by);
  if (bx > by) return;
  const int z = blockIdx.z, b = z >> 4, h = z & 15, kvh = h >> 2;
  const unsigned short* A = q + (size_t)b * 1024 * HIDDIM + h * HDIM;
  const unsigned short* W = k + (size_t)b * 1024 * KVDIM + kvh * HDIM;
  unsigned short* outp = s + (size_t)z * 1048576;
  const int m0 = by * 256, n0 = bx * 256;

  const int u0 = tid, u1 = tid + 512;
  const int r0s = u0 >> 3, r1s = u1 >> 3;
  const int c0 = ((u0 & 7) ^ (r0s & 7)) << 3, c1 = ((u1 & 7) ^ (r1s & 7)) << 3;
  const size_t offA0 = (size_t)r0s * HIDDIM + c0;
  const size_t offA1 = (size_t)r1s * HIDDIM + c1;
  const size_t offW0 = (size_t)r0s * KVDIM + c0;
  const size_t offW1 = (size_t)r1s * KVDIM + c1;
  const unsigned short* gb0 = A + (size_t)m0 * HIDDIM;
  const unsigned short* gb1 = A + (size_t)(m0 + 128) * HIDDIM;
  const unsigned short* gb2 = W + (size_t)n0 * KVDIM;
  const unsigned short* gb3 = W + (size_t)(n0 + 128) * KVDIM;

#define QSTAGE(h_, tt_, b_)                                                   \
  do {                                                                        \
    const unsigned short* _g =                                                \
        ((h_) == 0 ? gb0 : (h_) == 1 ? gb1 : (h_) == 2 ? gb2 : gb3) +         \
        (size_t)(tt_)*64;                                                     \
    const size_t _o0 = (h_) < 2 ? offA0 : offW0;                              \
    const size_t _o1 = (h_) < 2 ? offA1 : offW1;                              \
    unsigned short* _l = &lds[(b_)*32768 + (h_)*8192 + wave * 512];           \
    gload_lds16(_g + _o0, _l);                                                \
    gload_lds16(_g + _o1, _l + 4096);                                         \
  } while (0)

  const int e0 = lq ^ (fr & 7);
  const int cbA = wm * 8192;
  const int cbB = (2 + (wn >> 1)) * 8192;
  const int rB0 = (wn & 1) * 64 + fr;

#define QLDA(mi_, ks_, c_)                                                    \
  (*reinterpret_cast<const bf16x8*>(                                          \
      &lds[(c_)*32768 + cbA + ((mi_)*16 + fr) * 64 + ((e0 ^ ((ks_)*4)) << 3)]))
#define QLDB(ni_, ks_, c_)                                                    \
  (*reinterpret_cast<const bf16x8*>(                                          \
      &lds[(c_)*32768 + cbB + (rB0 + (ni_)*16) * 64 + ((e0 ^ ((ks_)*4)) << 3)]))

  f32x4 acc[8][4] = {};
  bf16x8 aF[4], bF[4];

  QSTAGE(0, 0, 0); QSTAGE(1, 0, 0); QSTAGE(2, 0, 0); QSTAGE(3, 0, 0);

  for (int t = 0; t < 2; ++t) {
    const int c = t & 1;
    if (t == 0) {
      QSTAGE(0, 1, 1); QSTAGE(2, 1, 1);
      asm volatile("s_waitcnt vmcnt(4)" ::: "memory");
    } else {
      asm volatile("s_waitcnt vmcnt(0)" ::: "memory");
    }
    BARRIER();
    bF[0] = QLDB(0, 0, c); bF[1] = QLDB(1, 0, c);
    bF[2] = QLDB(2, 0, c); bF[3] = QLDB(3, 0, c);
    aF[0] = QLDA(0, 0, c); aF[1] = QLDA(1, 0, c);
    aF[2] = QLDA(2, 0, c); aF[3] = QLDA(3, 0, c);
    if (t == 0) { QSTAGE(1, 1, 1); QSTAGE(3, 1, 1); }
    BARRIER();
    __builtin_amdgcn_s_setprio(1);
    mfma16<0>(aF, bF, acc);
    __builtin_amdgcn_s_setprio(0);
    __builtin_amdgcn_sched_barrier(0);
    BARRIER();
    aF[0] = QLDA(4, 0, c); aF[1] = QLDA(5, 0, c);
    aF[2] = QLDA(6, 0, c); aF[3] = QLDA(7, 0, c);
    BARRIER();
    __builtin_amdgcn_s_setprio(1);
    mfma16<4>(aF, bF, acc);
    __builtin_amdgcn_s_setprio(0);
    __builtin_amdgcn_sched_barrier(0);
    BARRIER();
    bF[0] = QLDB(0, 1, c); bF[1] = QLDB(1, 1, c);
    bF[2] = QLDB(2, 1, c); bF[3] = QLDB(3, 1, c);
    aF[0] = QLDA(0, 1, c); aF[1] = QLDA(1, 1, c);
    aF[2] = QLDA(2, 1, c); aF[3] = QLDA(3, 1, c);
    BARRIER();
    __builtin_amdgcn_s_setprio(1);
    mfma16<0>(aF, bF, acc);
    __builtin_amdgcn_s_setprio(0);
    __builtin_amdgcn_sched_barrier(0);
    BARRIER();
    aF[0] = QLDA(4, 1, c); aF[1] = QLDA(5, 1, c);
    aF[2] = QLDA(6, 1, c); aF[3] = QLDA(7, 1, c);
    BARRIER();
    __builtin_amdgcn_s_setprio(1);
    mfma16<4>(aF, bF, acc);
    __builtin_amdgcn_s_setprio(0);
    __builtin_amdgcn_sched_barrier(0);
    BARRIER();
  }

  const float scale = 0.08838834764831845f;
  const int r0 = lq * 4;
#pragma unroll
  for (int mi = 0; mi < 8; ++mi)
#pragma unroll
    for (int ni = 0; ni < 4; ++ni)
#pragma unroll
      for (int r = 0; r < 4; ++r) {
        const int gm = m0 + wm * 128 + mi * 16 + r0 + r;
        const int gn = n0 + wn * 64 + ni * 16 + fr;
        outp[(size_t)gm * 1024 + gn] = f2h(acc[mi][ni][r] * scale);
      }
#undef QSTAGE
#undef QLDA
#undef QLDB
}

// ---------------------------------------------------------------------------
__global__ __launch_bounds__(256) void softmax_rows(unsigned short* __restrict__ s) {
  const int row = blockIdx.x, tid = threadIdx.x;
  const int lane = tid & 63, wave = tid >> 6;
  const int qv = row & 1023;
  const int nact = ((qv >> 8) + 1) << 8;
  unsigned short* r = s + (size_t)row * 1024;
  const int col = tid * 4;
  const bool act = (col < nact);
  float v[4];
  if (act) {
    u16x4 raw = *reinterpret_cast<const u16x4*>(r + col);
#pragma unroll
    for (int j = 0; j < 4; ++j)
      v[j] = (col + j <= qv) ? h2f(((unsigned short*)&raw)[j]) : -1e30f;
  } else {
#pragma unroll
    for (int j = 0; j < 4; ++j) v[j] = -1e30f;
  }
  float mx = fmaxf(fmaxf(v[0], v[1]), fmaxf(v[2], v[3]));
#pragma unroll
  for (int off = 1; off < 64; off <<= 1) mx = fmaxf(mx, __shfl_xor(mx, off, 64));
  __shared__ float redm[4], reds[4];
  if (lane == 0) redm[wave] = mx;
  __syncthreads();
  const float M = fmaxf(fmaxf(redm[0], redm[1]), fmaxf(redm[2], redm[3]));
  float e[4], ts = 0.f;
#pragma unroll
  for (int j = 0; j < 4; ++j) {
    e[j] = (act && col + j <= qv) ? __expf(v[j] - M) : 0.f;
    ts += e[j];
  }
#pragma unroll
  for (int off = 1; off < 64; off <<= 1) ts += __shfl_xor(ts, off, 64);
  if (lane == 0) reds[wave] = ts;
  __syncthreads();
  const float inv = 1.f / (reds[0] + reds[1] + reds[2] + reds[3]);
  if (act) {
    u16x4 o;
    o.x = f2bf(e[0] * inv); o.y = f2bf(e[1] * inv);
    o.z = f2bf(e[2] * inv); o.w = f2bf(e[3] * inv);
    *reinterpret_cast<u16x4*>(r + col) = o;
  }
}

// ---------------------------------------------------------------------------
// PV GEMM: BM=256, BN=64, BK=64, 4 waves. NT = by*4+4. Grid (2,4,32).
// ---------------------------------------------------------------------------
__global__ __launch_bounds__(256, 2) void gemm_pv(
    const unsigned short* __restrict__ p, const unsigned short* __restrict__ vt,
    unsigned short* __restrict__ ao) {
  __shared__ unsigned short lds[40960];
  const int tid = threadIdx.x, lane = tid & 63, wave = tid >> 6;
  const int fr = lane & 15, lq = lane >> 4;
  const int bxn = blockIdx.x, by = blockIdx.y, z = blockIdx.z;
  const int b = z >> 4, h = z & 15, kvh = h >> 2;
  const int m0p = by * 256, n0 = bxn * 64;
  const int NT = by * 4 + 4;

  const unsigned short* A = p + (size_t)z * 1048576 + (size_t)m0p * 1024;
  const unsigned short* W =
      vt + ((size_t)(b * 4 + kvh) * 128 + n0) * 1024;

#define PVSTAGE(tt_, c_)                                                      \
  do {                                                                        \
    _Pragma("unroll")                                                         \
    for (int j = 0; j < 8; ++j) {                                             \
      const int u = wave * 512 + j * 64 + lane;                               \
      const int rw = u >> 3;                                                  \
      gload_lds16(A + (size_t)rw * 1024 + (((u & 7) ^ (rw & 7)) << 3) +       \
                      (size_t)(tt_)*64,                                       \
                  &lds[(c_)*20480 + wave * 4096 + j * 512]);                  \
    }                                                                         \
    _Pragma("unroll")                                                         \
    for (int j = 0; j < 2; ++j) {                                             \
      const int u = wave * 128 + j * 64 + lane;                               \
      const int rw = u >> 3;                                                  \
      gload_lds16(W + (size_t)rw * 1024 + (((u & 7) ^ (rw & 7)) << 3) +       \
                      (size_t)(tt_)*64,                                       \
                  &lds[(c_)*20480 + 16384 + wave * 1024 + j * 512]);          \
    }                                                                         \
  } while (0)

  const int e0 = lq ^ (fr & 7);
#define PVLDA(mi_, ks_, c_)                                                   \
  (*reinterpret_cast<const bf16x8*>(                                          \
      &lds[(c_)*20480 + (wave * 64 + (mi_)*16 + fr) * 64 +                    \
           ((e0 ^ ((ks_)*4)) << 3)]))
#define PVLDB(ni_, ks_, c_)                                                   \
  (*reinterpret_cast<const bf16x8*>(                                          \
      &lds[(c_)*20480 + 16384 + ((ni_)*16 + fr) * 64 +                        \
           ((e0 ^ ((ks_)*4)) << 3)]))

  f32x4 acc[4][4] = {};
  bf16x8 aF[4], bF[4];

  PVSTAGE(0, 0);

  for (int t = 0; t < NT; ++t) {
    const int c = t & 1;
    if (t + 1 < NT) {
      PVSTAGE(t + 1, c ^ 1);
      asm volatile("s_waitcnt vmcnt(10)" ::: "memory");
    } else {
      asm volatile("s_waitcnt vmcnt(0)" ::: "memory");
    }
    BARRIER();
#pragma unroll
    for (int ks = 0; ks < 2; ++ks) {
      bF[0] = PVLDB(0, ks, c); bF[1] = PVLDB(1, ks, c);
      bF[2] = PVLDB(2, ks, c); bF[3] = PVLDB(3, ks, c);
      aF[0] = PVLDA(0, ks, c); aF[1] = PVLDA(1, ks, c);
      aF[2] = PVLDA(2, ks, c); aF[3] = PVLDA(3, ks, c);
      BARRIER();
      __builtin_amdgcn_s_setprio(1);
#pragma unroll
      for (int ni = 0; ni < 4; ++ni)
#pragma unroll
        for (int mi = 0; mi < 4; ++mi)
          acc[mi][ni] = __builtin_amdgcn_mfma_f32_16x16x32_bf16(
              aF[mi], bF[ni], acc[mi][ni], 0, 0, 0);
      __builtin_amdgcn_s_setprio(0);
      __builtin_amdgcn_sched_barrier(0);
      BARRIER();
    }
  }

  const int r0 = lq * 4;
#pragma unroll
  for (int mi = 0; mi < 4; ++mi)
#pragma unroll
    for (int ni = 0; ni < 4; ++ni)
#pragma unroll
      for (int r = 0; r < 4; ++r) {
        const int gm = m0p + wave * 64 + mi * 16 + r0 + r;
        const int gn = n0 + ni * 16 + fr;
        ao[(size_t)(b * 1024 + gm) * HIDDIM + h * HDIM + gn] =
            f2bf(acc[mi][ni][r]);
      }
#undef PVSTAGE
#undef PVLDA
#undef PVLDB
}

// ---------------------------------------------------------------------------
// QKV split-K2 reduce (bf16 partials) + bias + RoPE + V-transpose.
// ---------------------------------------------------------------------------
__global__ __launch_bounds__(256) void reduce_qkv(
    const unsigned short* __restrict__ p, const float* __restrict__ qb,
    const float* __restrict__ kb, const float* __restrict__ vb,
    const float* __restrict__ cosb, const float* __restrict__ sinb,
    unsigned short* __restrict__ qo, unsigned short* __restrict__ ko,
    unsigned short* __restrict__ vto) {
  const int i = blockIdx.x * 256 + threadIdx.x;
  const int row = i / 768, c4 = (i - row * 768) * 4;
  const unsigned short* p0 = p + (size_t)row * 3072;
  const unsigned short* p1 = p + 6291456 + (size_t)row * 3072;
  const u16x4 a0 = *reinterpret_cast<const u16x4*>(p0 + c4);
  const u16x4 a1 = *reinterpret_cast<const u16x4*>(p1 + c4);
  f32x4 s;
  s.x = bf2f(a0.x) + bf2f(a1.x); s.y = bf2f(a0.y) + bf2f(a1.y);
  s.z = bf2f(a0.z) + bf2f(a1.z); s.w = bf2f(a0.w) + bf2f(a1.w);
  if (c4 < 2560) {
    const float* bias; unsigned short* out; int d, ldo;
    if (c4 < 2048) { bias = qb; out = qo; d = c4;        ldo = HIDDIM; }
    else           { bias = kb; out = ko; d = c4 - 2048; ldo = KVDIM; }
    const int dd = d & 127;
    const bool lohalf = (dd < 64);
    const int pc = lohalf ? c4 + 64 : c4 - 64;
    const int pd = lohalf ? d + 64 : d - 64;
    const u16x4 b0 = *reinterpret_cast<const u16x4*>(p0 + pc);
    const u16x4 b1 = *reinterpret_cast<const u16x4*>(p1 + pc);
    f32x4 sp;
    sp.x = bf2f(b0.x) + bf2f(b1.x); sp.y = bf2f(b0.y) + bf2f(b1.y);
    sp.z = bf2f(b0.z) + bf2f(b1.z); sp.w = bf2f(b0.w) + bf2f(b1.w);
    const f32x4 bv = *reinterpret_cast<const f32x4*>(bias + d);
    const f32x4 bp = *reinterpret_cast<const f32x4*>(bias + pd);
    const f32x4 cv = *reinterpret_cast<const f32x4*>(cosb + (size_t)row * 128 + dd);
    const f32x4 sv = *reinterpret_cast<const f32x4*>(sinb + (size_t)row * 128 + dd);
    const f32x4 xv = s + bv, pv = sp + bp;
    f32x4 o;
    if (lohalf) o = xv * cv - pv * sv;
    else        o = xv * cv + pv * sv;
    u16x4 ob;
    ob.x = f2bf(o.x); ob.y = f2bf(o.y); ob.z = f2bf(o.z); ob.w = f2bf(o.w);
    *reinterpret_cast<u16x4*>(out + (size_t)row * ldo + d) = ob;
  } else {
    const int d = c4 - 2560;
    const int kvh = d >> 7, dd = d & 127;
    const int b = row >> 10, t = row & 1023;
    const f32x4 bv = *reinterpret_cast<const f32x4*>(vb + d);
    const f32x4 o = s + bv;
    unsigned short* vr =
        vto + ((size_t)(b * 4 + kvh) * 128 + dd) * 1024 + t;
    vr[0] = f2bf(o.x); vr[1024] = f2bf(o.y);
    vr[2048] = f2bf(o.z); vr[3072] = f2bf(o.w);
  }
}

// ---------------------------------------------------------------------------
extern "C" void kernel_launch(void* const* d_in, const int* in_sizes, int n_in,
                              void* d_out, int out_size, void* d_ws,
                              size_t ws_size, hipStream_t stream) {
  (void)in_sizes; (void)n_in; (void)out_size; (void)ws_size;
  const float* hidden = (const float*)d_in[0];
  const float* cosb  = (const float*)d_in[1];
  const float* sinb  = (const float*)d_in[2];
  const float* qw    = (const float*)d_in[3];
  const float* qbias = (const float*)d_in[4];
  const float* kw    = (const float*)d_in[5];
  const float* kbias = (const float*)d_in[6];
  const float* vw    = (const float*)d_in[7];
  const float* vbias = (const float*)d_in[8];
  const float* ow    = (const float*)d_in[9];
  const float* gw    = (const float*)d_in[10];
  const float* uw    = (const float*)d_in[11];
  const float* dw    = (const float*)d_in[12];
  const float* ln1   = (const float*)d_in[13];
  const float* ln2   = (const float*)d_in[14];
  const float* normw = (const float*)d_in[15];

  char* ws = (char*)d_ws;
  float* x               = (float*)ws;                          // 0      16.8M
  unsigned short* hbuf   = (unsigned short*)(ws + 16777216);    // 16.8M   8.4M
  unsigned short* qbuf   = (unsigned short*)(ws + 25165824);    // 25.2M   8.4M
  unsigned short* kbuf   = (unsigned short*)(ws + 33554432);    // 33.6M   2.1M
  unsigned short* vtbuf  = (unsigned short*)(ws + 35651584);    // 35.7M   2.1M
  unsigned short* aobuf  = (unsigned short*)(ws + 39845888);    // 39.8M   8.4M
  unsigned short* actbuf = (unsigned short*)(ws + 71303168);    // 71.3M  23.1M
  unsigned short* wcvt   = (unsigned short*)(ws + 94371840);    // 94.4M  23.1M
  // Overlays (dead regions at time-of-use, stream-serialized):
  unsigned short* pbQKV = (unsigned short*)(ws + 37748736);  // 2x12.6MB
  unsigned short* sbuf  = (unsigned short*)(ws + 48234496);  // 67MB S/P planes
  unsigned short* pbO   = (unsigned short*)(ws + 48234496);  // 4x8.4MB
  unsigned short* wgu   = (unsigned short*)(ws + 25165824);  // 46.1MB
  unsigned short* pbD   = (unsigned short*)(ws + 25165824);  // 4x8.4MB

  unsigned short* wq16 = wcvt;
  unsigned short* wk16 = wcvt + 4194304;
  unsigned short* wv16 = wcvt + 5242880;
  unsigned short* ow16 = wcvt;

  hipMemcpyAsync(x, hidden, (size_t)NTOK * HIDDIM * 4,
                 hipMemcpyDeviceToDevice, stream);
  rmsnorm_kernel<0><<<NTOK, 256, 0, stream>>>(x, ln1, hbuf);

  for (int l = 0; l < 4; ++l) {
    const float* qw_l = qw + (size_t)l * 2048 * 2048;
    const float* qb_l = qbias + (size_t)l * 2048;
    const float* kw_l = kw + (size_t)l * 512 * 2048;
    const float* kb_l = kbias + (size_t)l * 512;
    const float* vw_l = vw + (size_t)l * 512 * 2048;
    const float* vb_l = vbias + (size_t)l * 512;
    const float* ow_l = ow + (size_t)l * 2048 * 2048;
    const float* gw_l = gw + (size_t)l * 5632 * 2048;
    const float* uw_l = uw + (size_t)l * 5632 * 2048;
    const float* dw_l = dw + (size_t)l * 2048 * 5632;

    cvt_kernel<<<2048, 256, 0, stream>>>(qw_l, wq16, 524288);
    cvt_kernel<<<512, 256, 0, stream>>>(kw_l, wk16, 131072);
    cvt_kernel<<<512, 256, 0, stream>>>(vw_l, wv16, 131072);
    // fused QKV: [2048,2048] x [3072,2048]^T, split-K2 (sub-K=32: 64 subtiles)
    gemm16w<<<dim3(12, 8, 2), 1024, 0, stream>>>(
        hbuf, wcvt, pbQKV, 2048, 3072, 32, 64, (size_t)6291456);
    reduce_qkv<<<6144, 256, 0, stream>>>(pbQKV, qb_l, kb_l, vb_l, cosb, sinb,
                                         qbuf, kbuf, vtbuf);

    gemm_qk<<<dim3(4, 4, 32), 512, 0, stream>>>(qbuf, kbuf, sbuf);
    softmax_rows<<<32768, 256, 0, stream>>>(sbuf);
    gemm_pv<<<dim3(2, 4, 32), 256, 0, stream>>>(sbuf, vtbuf, aobuf);

    // O-proj: split-K4
    cvt_kernel<<<2048, 256, 0, stream>>>(ow_l, ow16, 524288);
    gemm16w<<<dim3(8, 8, 4), 1024, 0, stream>>>(
        aobuf, ow16, pbO, 2048, 2048, 16, 64, (size_t)4194304);
    reduce_rms<4, 0><<<NTOK, 256, 0, stream>>>(x, pbO, (size_t)4194304,
                                               ln2 + l * 2048, hbuf);

    // gate+up fused (8-wave BK=64 8-phase, by-major XCD decode)
    cvt_gu<<<11264, 256, 0, stream>>>(gw_l, uw_l, wgu);
    gemm_gu<<<dim3(44, 8), 512, 0, stream>>>(hbuf, wgu, actbuf);

    // down: split-K4 (K=5632 -> 176 subtiles -> 44/split)
    cvt_kernel<<<5632, 256, 0, stream>>>(dw_l, wcvt, 1441792);
    gemm16w<<<dim3(8, 8, 4), 1024, 0, stream>>>(
        actbuf, wcvt, pbD, 5632, 2048, 44, 176, (size_t)4194304);
    if (l < 3) {
      reduce_rms<4, 0><<<NTOK, 256, 0, stream>>>(
          x, pbD, (size_t)4194304, ln1 + (l + 1) * 2048, hbuf);
    } else {
      reduce_rms<4, 1><<<NTOK, 256, 0, stream>>>(x, pbD, (size_t)4194304,
                                                 normw, d_out);
    }
  }
}

// Round 13
// 1555.766 us; speedup vs baseline: 1.0958x; 1.0408x over previous
//
#include <hip/hip_runtime.h>

// ---------------------------------------------------------------------------
// DecoderBackbone: 4-layer llama-style decoder, B=2 T=1024 HID=2048,
// NH=16 NKV=4 HD=128, INTER=5632. fp32 residual stream, bf16 MFMA GEMMs.
// R13 = R12 with the overlay bug fixed: the O-weight convert done by
// gemm_qk's causal-dead blocks now targets the HBUF region (dead during
// attention), NOT wcvt — wcvt's tail is aliased by sbuf planes 22-31 and
// was being clobbered (R12 absmax 4.16). GU z=1 aux cvt (dw -> wcvt) is
// safe: sbuf is dead by gemm_gu time. Softmax 64-col trim kept.
// ---------------------------------------------------------------------------

typedef __attribute__((ext_vector_type(8))) __bf16 bf16x8;
typedef __attribute__((ext_vector_type(4))) float f32x4;
typedef __attribute__((ext_vector_type(4))) unsigned short u16x4;

#define DEV __device__ __forceinline__
#define BARRIER() asm volatile("s_barrier" ::: "memory")

#define NTOK 2048
#define HIDDIM 2048
#define KVDIM 512
#define HDIM 128
#define INTERDIM 5632

DEV unsigned short f2bf(float f) {
  union { float f; unsigned u; } a; a.f = f;
  unsigned r = a.u + 0x7fffu + ((a.u >> 16) & 1u);
  return (unsigned short)(r >> 16);
}
DEV float bf2f(unsigned short h) {
  union { unsigned u; float f; } a; a.u = ((unsigned)h) << 16;
  return a.f;
}
DEV unsigned short f2h(float f) {
  union { _Float16 h; unsigned short u; } c; c.h = (_Float16)f; return c.u;
}
DEV float h2f(unsigned short u) {
  union { unsigned short u; _Float16 h; } c; c.u = u; return (float)c.h;
}
DEV void gload_lds16(const void* g, void* l) {
  __builtin_amdgcn_global_load_lds(
      (const __attribute__((address_space(1))) unsigned int*)(g),
      (__attribute__((address_space(3))) unsigned int*)(l), 16, 0, 0);
}
DEV void cvt8(const float* __restrict__ in, unsigned short* __restrict__ out,
              int i) {
  const f32x4* p = reinterpret_cast<const f32x4*>(in) + (size_t)i * 2;
  const f32x4 a = p[0], b = p[1];
  bf16x8 o;
  o[0] = (__bf16)a.x; o[1] = (__bf16)a.y; o[2] = (__bf16)a.z; o[3] = (__bf16)a.w;
  o[4] = (__bf16)b.x; o[5] = (__bf16)b.y; o[6] = (__bf16)b.z; o[7] = (__bf16)b.w;
  *reinterpret_cast<bf16x8*>(out + (size_t)i * 8) = o;
}

// XCD-aware bijective decode, by-major within XCD chunk (R11: keeps W panels
// L2-resident per XCD; FETCH -51% measured).
DEV void xcd_decode(int& bx, int& by) {
  const int nbx = gridDim.x, nby = gridDim.y;
  const int nwg = nbx * nby;
  const int lin = by * nbx + bx, cpx = nwg >> 3;
  const int swz = (lin & 7) * cpx + (lin >> 3);
  by = swz % nby;
  bx = swz / nby;
}

// ---------------------------------------------------------------------------
__global__ __launch_bounds__(256) void cvt_kernel(
    const float* __restrict__ in, unsigned short* __restrict__ out, int n8) {
  const int i = blockIdx.x * 256 + threadIdx.x;
  if (i >= n8) return;
  cvt8(in, out, i);
}

// Interleaved gate/up convert: out[11264][2048], per 256-row group t:
// rows t*256..+127 = gate rows t*128.., rows +128.. = up rows t*128..
__global__ __launch_bounds__(256) void cvt_gu(
    const float* __restrict__ gw, const float* __restrict__ uw,
    unsigned short* __restrict__ out) {
  const int i = blockIdx.x * 256 + threadIdx.x;
  const int row = i >> 8, g8 = i & 255;
  const int t = row >> 8, sub = row & 255;
  const float* src = (sub < 128)
                         ? gw + (size_t)(t * 128 + sub) * 2048
                         : uw + (size_t)(t * 128 + sub - 128) * 2048;
  const f32x4* p = reinterpret_cast<const f32x4*>(src) + (size_t)g8 * 2;
  const f32x4 a = p[0], b = p[1];
  bf16x8 o;
  o[0] = (__bf16)a.x; o[1] = (__bf16)a.y; o[2] = (__bf16)a.z; o[3] = (__bf16)a.w;
  o[4] = (__bf16)b.x; o[5] = (__bf16)b.y; o[6] = (__bf16)b.z; o[7] = (__bf16)b.w;
  *reinterpret_cast<bf16x8*>(out + (size_t)row * 2048 + g8 * 8) = o;
}

// ---------------------------------------------------------------------------
template <int OUTF32>
__global__ __launch_bounds__(256) void rmsnorm_kernel(
    const float* __restrict__ x, const float* __restrict__ w,
    void* __restrict__ outp) {
  const int row = blockIdx.x, tid = threadIdx.x;
  const int lane = tid & 63, wave = tid >> 6;
  const float* xr = x + (size_t)row * HIDDIM;
  f32x4 v0 = *reinterpret_cast<const f32x4*>(xr + tid * 4);
  f32x4 v1 = *reinterpret_cast<const f32x4*>(xr + 1024 + tid * 4);
  float ss = v0.x * v0.x + v0.y * v0.y + v0.z * v0.z + v0.w * v0.w +
             v1.x * v1.x + v1.y * v1.y + v1.z * v1.z + v1.w * v1.w;
#pragma unroll
  for (int off = 1; off < 64; off <<= 1) ss += __shfl_xor(ss, off, 64);
  __shared__ float red[4];
  if (lane == 0) red[wave] = ss;
  __syncthreads();
  ss = red[0] + red[1] + red[2] + red[3];
  const float rs = rsqrtf(ss * (1.0f / 2048.0f) + 1e-6f);
  f32x4 w0 = *reinterpret_cast<const f32x4*>(w + tid * 4);
  f32x4 w1 = *reinterpret_cast<const f32x4*>(w + 1024 + tid * 4);
  if (OUTF32) {
    float* o = (float*)outp + (size_t)row * HIDDIM;
    f32x4 o0, o1;
    o0.x = v0.x * rs * w0.x; o0.y = v0.y * rs * w0.y;
    o0.z = v0.z * rs * w0.z; o0.w = v0.w * rs * w0.w;
    o1.x = v1.x * rs * w1.x; o1.y = v1.y * rs * w1.y;
    o1.z = v1.z * rs * w1.z; o1.w = v1.w * rs * w1.w;
    *reinterpret_cast<f32x4*>(o + tid * 4) = o0;
    *reinterpret_cast<f32x4*>(o + 1024 + tid * 4) = o1;
  } else {
    unsigned short* o = (unsigned short*)outp + (size_t)row * HIDDIM;
    u16x4 p0, p1;
    p0.x = f2bf(v0.x * rs * w0.x); p0.y = f2bf(v0.y * rs * w0.y);
    p0.z = f2bf(v0.z * rs * w0.z); p0.w = f2bf(v0.w * rs * w0.w);
    p1.x = f2bf(v1.x * rs * w1.x); p1.y = f2bf(v1.y * rs * w1.y);
    p1.z = f2bf(v1.z * rs * w1.z); p1.w = f2bf(v1.w * rs * w1.w);
    *reinterpret_cast<u16x4*>(o + tid * 4) = p0;
    *reinterpret_cast<u16x4*>(o + 1024 + tid * 4) = p1;
  }
}

// Fused split-K reduce + residual add + RMSNorm (bf16 partial planes).
template <int KS, int OUTF32>
__global__ __launch_bounds__(256) void reduce_rms(
    float* __restrict__ x, const unsigned short* __restrict__ p, size_t zs,
    const float* __restrict__ w, void* __restrict__ outp) {
  const int row = blockIdx.x, tid = threadIdx.x;
  const int lane = tid & 63, wave = tid >> 6;
  float* xr = x + (size_t)row * HIDDIM;
  f32x4 v0 = *reinterpret_cast<const f32x4*>(xr + tid * 4);
  f32x4 v1 = *reinterpret_cast<const f32x4*>(xr + 1024 + tid * 4);
#pragma unroll
  for (int s = 0; s < KS; ++s) {
    const unsigned short* pr = p + (size_t)s * zs + (size_t)row * HIDDIM;
    u16x4 a = *reinterpret_cast<const u16x4*>(pr + tid * 4);
    u16x4 b = *reinterpret_cast<const u16x4*>(pr + 1024 + tid * 4);
    v0.x += bf2f(a.x); v0.y += bf2f(a.y); v0.z += bf2f(a.z); v0.w += bf2f(a.w);
    v1.x += bf2f(b.x); v1.y += bf2f(b.y); v1.z += bf2f(b.z); v1.w += bf2f(b.w);
  }
  *reinterpret_cast<f32x4*>(xr + tid * 4) = v0;
  *reinterpret_cast<f32x4*>(xr + 1024 + tid * 4) = v1;
  float ss = v0.x * v0.x + v0.y * v0.y + v0.z * v0.z + v0.w * v0.w +
             v1.x * v1.x + v1.y * v1.y + v1.z * v1.z + v1.w * v1.w;
#pragma unroll
  for (int off = 1; off < 64; off <<= 1) ss += __shfl_xor(ss, off, 64);
  __shared__ float red[4];
  if (lane == 0) red[wave] = ss;
  __syncthreads();
  ss = red[0] + red[1] + red[2] + red[3];
  const float rs = rsqrtf(ss * (1.0f / 2048.0f) + 1e-6f);
  f32x4 w0 = *reinterpret_cast<const f32x4*>(w + tid * 4);
  f32x4 w1 = *reinterpret_cast<const f32x4*>(w + 1024 + tid * 4);
  if (OUTF32) {
    float* o = (float*)outp + (size_t)row * HIDDIM;
    f32x4 o0, o1;
    o0.x = v0.x * rs * w0.x; o0.y = v0.y * rs * w0.y;
    o0.z = v0.z * rs * w0.z; o0.w = v0.w * rs * w0.w;
    o1.x = v1.x * rs * w1.x; o1.y = v1.y * rs * w1.y;
    o1.z = v1.z * rs * w1.z; o1.w = v1.w * rs * w1.w;
    *reinterpret_cast<f32x4*>(o + tid * 4) = o0;
    *reinterpret_cast<f32x4*>(o + 1024 + tid * 4) = o1;
  } else {
    unsigned short* o = (unsigned short*)outp + (size_t)row * HIDDIM;
    u16x4 p0, p1;
    p0.x = f2bf(v0.x * rs * w0.x); p0.y = f2bf(v0.y * rs * w0.y);
    p0.z = f2bf(v0.z * rs * w0.z); p0.w = f2bf(v0.w * rs * w0.w);
    p1.x = f2bf(v1.x * rs * w1.x); p1.y = f2bf(v1.y * rs * w1.y);
    p1.z = f2bf(v1.z * rs * w1.z); p1.w = f2bf(v1.w * rs * w1.w);
    *reinterpret_cast<u16x4*>(o + tid * 4) = p0;
    *reinterpret_cast<u16x4*>(o + 1024 + tid * 4) = p1;
  }
}

// ---------------------------------------------------------------------------
// mfma16: one 16-MFMA cluster of an acc[8][4] wave tile (8-wave kernels).
// ---------------------------------------------------------------------------
template <int MB>
DEV void mfma16(const bf16x8 (&aF)[4], const bf16x8 (&bF)[4],
                f32x4 (&acc)[8][4]) {
#pragma unroll
  for (int ni = 0; ni < 4; ++ni)
#pragma unroll
    for (int mi = 0; mi < 4; ++mi)
      acc[MB + mi][ni] = __builtin_amdgcn_mfma_f32_16x16x32_bf16(
          aF[mi], bF[ni], acc[MB + mi][ni], 0, 0, 0);
}

// ---------------------------------------------------------------------------
// gemm16w (R9): 256x256 tile, 16 waves (4Mx4N, 64x64/wave), BK=32, 64KB LDS
// dbuf, counted vmcnt(2), XOR slot swizzle both sides. bf16 partial planes.
// ---------------------------------------------------------------------------
struct G16Setup {
  const unsigned short* srcp0;
  const unsigned short* srcp1;
  int ldsc0, ldsc1;
};

DEV G16Setup g16_setup(const unsigned short* A, const unsigned short* W,
                       int K, int m0, int n0, int t0, int wave, int lane) {
  const int c0 = wave * 2, c1 = wave * 2 + 1;
  const int rA = lane >> 2;
  const int cg = (((lane & 3) ^ ((lane >> 3) & 3))) * 8;   // swizzled src slot
  G16Setup s;
  const unsigned short* gb[4] = {
      A + (size_t)m0 * K, A + (size_t)(m0 + 128) * K,
      W + (size_t)n0 * K, W + (size_t)(n0 + 128) * K};
  s.srcp0 = gb[c0 >> 3] + (size_t)((c0 & 7) * 16 + rA) * K + cg +
            (size_t)t0 * 32;
  s.srcp1 = gb[c1 >> 3] + (size_t)((c1 & 7) * 16 + rA) * K + cg +
            (size_t)t0 * 32;
  s.ldsc0 = c0 * 512;
  s.ldsc1 = c1 * 512;
  return s;
}

#define G16STAGE(st_, tt_, c_)                                                \
  do {                                                                        \
    gload_lds16(st_.srcp0 + (size_t)(tt_)*32, &lds[(c_)*16384 + st_.ldsc0]);  \
    gload_lds16(st_.srcp1 + (size_t)(tt_)*32, &lds[(c_)*16384 + st_.ldsc1]);  \
  } while (0)

#define G16LDA(mi_, c_)                                                       \
  (*reinterpret_cast<const bf16x8*>(                                          \
      &lds[(c_)*16384 + (wm >> 1) * 4096 +                                    \
           (((wm & 1) * 64) + (mi_)*16 + fr) * 32 +                           \
           ((lq ^ ((fr >> 1) & 3))) * 8]))
#define G16LDB(ni_, c_)                                                       \
  (*reinterpret_cast<const bf16x8*>(                                          \
      &lds[(c_)*16384 + (2 + (wn >> 1)) * 4096 +                              \
           (((wn & 1) * 64) + (ni_)*16 + fr) * 32 +                           \
           ((lq ^ ((fr >> 1) & 3))) * 8]))

#define G16KLOOP(NT_)                                                         \
  G16STAGE(st, 0, 0);                                                         \
  for (int t = 0; t < (NT_); ++t) {                                           \
    const int c = t & 1;                                                      \
    if (t + 1 < (NT_)) {                                                      \
      G16STAGE(st, t + 1, c ^ 1);                                             \
      asm volatile("s_waitcnt vmcnt(2)" ::: "memory");                        \
    } else {                                                                  \
      asm volatile("s_waitcnt vmcnt(0)" ::: "memory");                        \
    }                                                                         \
    BARRIER();                                                                \
    bf16x8 aF[4], bF[4];                                                      \
    bF[0] = G16LDB(0, c); bF[1] = G16LDB(1, c);                               \
    bF[2] = G16LDB(2, c); bF[3] = G16LDB(3, c);                               \
    aF[0] = G16LDA(0, c); aF[1] = G16LDA(1, c);                               \
    aF[2] = G16LDA(2, c); aF[3] = G16LDA(3, c);                               \
    __builtin_amdgcn_s_setprio(1);                                            \
    _Pragma("unroll") for (int ni = 0; ni < 4; ++ni)                          \
        _Pragma("unroll") for (int mi = 0; mi < 4; ++mi)                      \
            acc[mi][ni] = __builtin_amdgcn_mfma_f32_16x16x32_bf16(            \
                aF[mi], bF[ni], acc[mi][ni], 0, 0, 0);                        \
    __builtin_amdgcn_s_setprio(0);                                            \
    __builtin_amdgcn_sched_barrier(0);                                        \
    BARRIER();                                                                \
  }

__global__ __launch_bounds__(1024) void gemm16w(
    const unsigned short* __restrict__ A, const unsigned short* __restrict__ W,
    unsigned short* __restrict__ outp, int K, int ldo, int kt_split,
    int kt_tot, size_t zstride) {
  __shared__ unsigned short lds[32768];   // 64 KB
  const int tid = threadIdx.x, lane = tid & 63, wave = tid >> 6;
  const int fr = lane & 15, lq = lane >> 4;
  const int wm = wave >> 2, wn = wave & 3;

  int bx = blockIdx.x, by = blockIdx.y;
  xcd_decode(bx, by);
  const int m0 = by * 256, n0 = bx * 256;
  const int bz = blockIdx.z;
  const int t0 = bz * kt_split;
  int NT = kt_tot - t0; if (NT > kt_split) NT = kt_split;

  G16Setup st = g16_setup(A, W, K, m0, n0, t0, wave, lane);
  f32x4 acc[4][4] = {};
  G16KLOOP(NT);

  const int r0 = lq * 4;
#pragma unroll
  for (int mi = 0; mi < 4; ++mi)
#pragma unroll
    for (int ni = 0; ni < 4; ++ni)
#pragma unroll
      for (int r = 0; r < 4; ++r) {
        const int gm = m0 + wm * 64 + mi * 16 + r0 + r;
        const int gn = n0 + wn * 64 + ni * 16 + fr;
        outp[(size_t)bz * zstride + (size_t)gm * ldo + gn] =
            f2bf(acc[mi][ni][r]);
      }
}

// ---------------------------------------------------------------------------
// gemm_gu (R7 8-wave BK=64 8-phase): W = wgu[11264][2048] interleaved;
// epilogue exchanges gate values through LDS (f32) and stores silu(g)*u.
// z==1 aux plane: converts the down weights fp32->bf16 into wcvt (safe:
// sbuf — which aliases wcvt's tail — is dead by gemm_gu time).
// ---------------------------------------------------------------------------
__global__ __launch_bounds__(512, 2) void gemm_gu(
    const unsigned short* __restrict__ A, const unsigned short* __restrict__ W,
    unsigned short* __restrict__ act, const float* __restrict__ dwsrc,
    unsigned short* __restrict__ dwdst) {
  __shared__ unsigned short lds[65536];
  const int tid = threadIdx.x, lane = tid & 63, wave = tid >> 6;
  const int fr = lane & 15, lq = lane >> 4;
  const int wm = wave >> 2, wn = wave & 3;
  const int K = 2048;

  if (blockIdx.z == 1) {   // aux: cvt down weights, 1441792 groups of 8
    const int blk = blockIdx.y * 44 + blockIdx.x;
    for (int i = blk * 512 + tid; i < 1441792; i += 352 * 512)
      cvt8(dwsrc, dwdst, i);
    return;
  }

  int bx = blockIdx.x, by = blockIdx.y;
  xcd_decode(bx, by);
  const int m0 = by * 256, n0 = bx * 256;

  const int u0 = tid, u1 = tid + 512;
  const int r0s = u0 >> 3, r1s = u1 >> 3;
  const size_t off0 = (size_t)r0s * K + (size_t)((((u0 & 7) ^ (r0s & 7))) << 3);
  const size_t off1 = (size_t)r1s * K + (size_t)((((u1 & 7) ^ (r1s & 7))) << 3);
  const unsigned short* gb0 = A + (size_t)(m0)*K;
  const unsigned short* gb1 = A + (size_t)(m0 + 128) * K;
  const unsigned short* gb2 = W + (size_t)(n0)*K;
  const unsigned short* gb3 = W + (size_t)(n0 + 128) * K;

#define STAGE(h_, tt_, b_)                                                    \
  do {                                                                        \
    const unsigned short* _g =                                                \
        ((h_) == 0 ? gb0 : (h_) == 1 ? gb1 : (h_) == 2 ? gb2 : gb3) +         \
        (size_t)(tt_)*64;                                                     \
    unsigned short* _l = &lds[(b_)*32768 + (h_)*8192 + wave * 512];           \
    gload_lds16(_g + off0, _l);                                               \
    gload_lds16(_g + off1, _l + 4096);                                        \
  } while (0)

  const int e0 = lq ^ (fr & 7);
  const int cbA = wm * 8192;
  const int cbB = (2 + (wn >> 1)) * 8192;
  const int rB0 = (wn & 1) * 64 + fr;

#define LDA(mi_, ks_, c_)                                                     \
  (*reinterpret_cast<const bf16x8*>(                                          \
      &lds[(c_)*32768 + cbA + ((mi_)*16 + fr) * 64 + ((e0 ^ ((ks_)*4)) << 3)]))
#define LDB(ni_, ks_, c_)                                                     \
  (*reinterpret_cast<const bf16x8*>(                                          \
      &lds[(c_)*32768 + cbB + (rB0 + (ni_)*16) * 64 + ((e0 ^ ((ks_)*4)) << 3)]))

  f32x4 acc[8][4] = {};
  bf16x8 aF[4], bF[4];

  STAGE(0, 0, 0); STAGE(1, 0, 0); STAGE(2, 0, 0); STAGE(3, 0, 0);

  for (int t = 0; t < 32; ++t) {
    const int c = t & 1;
    if (t + 1 < 32) {
      STAGE(0, t + 1, c ^ 1);
      STAGE(2, t + 1, c ^ 1);
      asm volatile("s_waitcnt vmcnt(4)" ::: "memory");
    } else {
      asm volatile("s_waitcnt vmcnt(0)" ::: "memory");
    }
    BARRIER();
    bF[0] = LDB(0, 0, c); bF[1] = LDB(1, 0, c);
    bF[2] = LDB(2, 0, c); bF[3] = LDB(3, 0, c);
    aF[0] = LDA(0, 0, c); aF[1] = LDA(1, 0, c);
    aF[2] = LDA(2, 0, c); aF[3] = LDA(3, 0, c);
    if (t + 1 < 32) { STAGE(1, t + 1, c ^ 1); STAGE(3, t + 1, c ^ 1); }
    BARRIER();
    __builtin_amdgcn_s_setprio(1);
    mfma16<0>(aF, bF, acc);
    __builtin_amdgcn_s_setprio(0);
    __builtin_amdgcn_sched_barrier(0);
    BARRIER();
    aF[0] = LDA(4, 0, c); aF[1] = LDA(5, 0, c);
    aF[2] = LDA(6, 0, c); aF[3] = LDA(7, 0, c);
    BARRIER();
    __builtin_amdgcn_s_setprio(1);
    mfma16<4>(aF, bF, acc);
    __builtin_amdgcn_s_setprio(0);
    __builtin_amdgcn_sched_barrier(0);
    BARRIER();
    bF[0] = LDB(0, 1, c); bF[1] = LDB(1, 1, c);
    bF[2] = LDB(2, 1, c); bF[3] = LDB(3, 1, c);
    aF[0] = LDA(0, 1, c); aF[1] = LDA(1, 1, c);
    aF[2] = LDA(2, 1, c); aF[3] = LDA(3, 1, c);
    BARRIER();
    __builtin_amdgcn_s_setprio(1);
    mfma16<0>(aF, bF, acc);
    __builtin_amdgcn_s_setprio(0);
    __builtin_amdgcn_sched_barrier(0);
    BARRIER();
    aF[0] = LDA(4, 1, c); aF[1] = LDA(5, 1, c);
    aF[2] = LDA(6, 1, c); aF[3] = LDA(7, 1, c);
    BARRIER();
    __builtin_amdgcn_s_setprio(1);
    mfma16<4>(aF, bF, acc);
    __builtin_amdgcn_s_setprio(0);
    __builtin_amdgcn_sched_barrier(0);
    BARRIER();
  }

  // epilogue: exchange gate values through LDS (f32 view, 32768 floats)
  float* fl = reinterpret_cast<float*>(lds);
  const int r0 = lq * 4;
  __syncthreads();
  if (wn < 2) {
#pragma unroll
    for (int mi = 0; mi < 8; ++mi)
#pragma unroll
      for (int ni = 0; ni < 4; ++ni)
#pragma unroll
        for (int r = 0; r < 4; ++r)
          fl[wm * 16384 + (mi * 16 + r0 + r) * 128 + wn * 64 + ni * 16 + fr] =
              acc[mi][ni][r];
  }
  __syncthreads();
  if (wn >= 2) {
    const int wnu = wn - 2;
#pragma unroll
    for (int mi = 0; mi < 8; ++mi)
#pragma unroll
      for (int ni = 0; ni < 4; ++ni)
#pragma unroll
        for (int r = 0; r < 4; ++r) {
          const int mrow = mi * 16 + r0 + r;
          const float gv = fl[wm * 16384 + mrow * 128 + wnu * 64 + ni * 16 + fr];
          const float s = gv / (1.f + __expf(-gv));
          const int gm = m0 + wm * 128 + mrow;
          const int ic = (n0 >> 1) + wnu * 64 + ni * 16 + fr;
          act[(size_t)gm * INTERDIM + ic] = f2bf(s * acc[mi][ni][r]);
        }
  }
#undef STAGE
#undef LDA
#undef LDB
}

// ---------------------------------------------------------------------------
// QK^T GEMM (8-wave, BK=64): S = (Q.K^T)*scale, f16 out. Causal-dead blocks
// (bx>by, 192 of 512) convert the O weights into the HBUF region (dead
// during attention; NOT wcvt — wcvt aliases sbuf planes 22-31).
// ---------------------------------------------------------------------------
__global__ __launch_bounds__(512, 2) void gemm_qk(
    const unsigned short* __restrict__ q, const unsigned short* __restrict__ k,
    unsigned short* __restrict__ s, const float* __restrict__ owsrc,
    unsigned short* __restrict__ owdst) {
  __shared__ unsigned short lds[65536];
  const int tid = threadIdx.x, lane = tid & 63, wave = tid >> 6;
  const int fr = lane & 15, lq = lane >> 4;
  const int wm = wave >> 2, wn = wave & 3;

  int bx = blockIdx.x, by = blockIdx.y;
  xcd_decode(bx, by);
  if (bx > by) {  // causal-dead: do a slice of the O-weight cvt (524288 grp8)
    const int did = blockIdx.z * 6 + ((bx * (bx - 1)) >> 1) + by;
    for (int i = did * 512 + tid; i < 524288; i += 192 * 512)
      cvt8(owsrc, owdst, i);
    return;
  }
  const int z = blockIdx.z, b = z >> 4, h = z & 15, kvh = h >> 2;
  const unsigned short* A = q + (size_t)b * 1024 * HIDDIM + h * HDIM;
  const unsigned short* W = k + (size_t)b * 1024 * KVDIM + kvh * HDIM;
  unsigned short* outp = s + (size_t)z * 1048576;
  const int m0 = by * 256, n0 = bx * 256;

  const int u0 = tid, u1 = tid + 512;
  const int r0s = u0 >> 3, r1s = u1 >> 3;
  const int c0 = ((u0 & 7) ^ (r0s & 7)) << 3, c1 = ((u1 & 7) ^ (r1s & 7)) << 3;
  const size_t offA0 = (size_t)r0s * HIDDIM + c0;
  const size_t offA1 = (size_t)r1s * HIDDIM + c1;
  const size_t offW0 = (size_t)r0s * KVDIM + c0;
  const size_t offW1 = (size_t)r1s * KVDIM + c1;
  const unsigned short* gb0 = A + (size_t)m0 * HIDDIM;
  const unsigned short* gb1 = A + (size_t)(m0 + 128) * HIDDIM;
  const unsigned short* gb2 = W + (size_t)n0 * KVDIM;
  const unsigned short* gb3 = W + (size_t)(n0 + 128) * KVDIM;

#define QSTAGE(h_, tt_, b_)                                                   \
  do {                                                                        \
    const unsigned short* _g =                                                \
        ((h_) == 0 ? gb0 : (h_) == 1 ? gb1 : (h_) == 2 ? gb2 : gb3) +         \
        (size_t)(tt_)*64;                                                     \
    const size_t _o0 = (h_) < 2 ? offA0 : offW0;                              \
    const size_t _o1 = (h_) < 2 ? offA1 : offW1;                              \
    unsigned short* _l = &lds[(b_)*32768 + (h_)*8192 + wave * 512];           \
    gload_lds16(_g + _o0, _l);                                                \
    gload_lds16(_g + _o1, _l + 4096);                                         \
  } while (0)

  const int e0 = lq ^ (fr & 7);
  const int cbA = wm * 8192;
  const int cbB = (2 + (wn >> 1)) * 8192;
  const int rB0 = (wn & 1) * 64 + fr;

#define QLDA(mi_, ks_, c_)                                                    \
  (*reinterpret_cast<const bf16x8*>(                                          \
      &lds[(c_)*32768 + cbA + ((mi_)*16 + fr) * 64 + ((e0 ^ ((ks_)*4)) << 3)]))
#define QLDB(ni_, ks_, c_)                                                    \
  (*reinterpret_cast<const bf16x8*>(                                          \
      &lds[(c_)*32768 + cbB + (rB0 + (ni_)*16) * 64 + ((e0 ^ ((ks_)*4)) << 3)]))

  f32x4 acc[8][4] = {};
  bf16x8 aF[4], bF[4];

  QSTAGE(0, 0, 0); QSTAGE(1, 0, 0); QSTAGE(2, 0, 0); QSTAGE(3, 0, 0);

  for (int t = 0; t < 2; ++t) {
    const int c = t & 1;
    if (t == 0) {
      QSTAGE(0, 1, 1); QSTAGE(2, 1, 1);
      asm volatile("s_waitcnt vmcnt(4)" ::: "memory");
    } else {
      asm volatile("s_waitcnt vmcnt(0)" ::: "memory");
    }
    BARRIER();
    bF[0] = QLDB(0, 0, c); bF[1] = QLDB(1, 0, c);
    bF[2] = QLDB(2, 0, c); bF[3] = QLDB(3, 0, c);
    aF[0] = QLDA(0, 0, c); aF[1] = QLDA(1, 0, c);
    aF[2] = QLDA(2, 0, c); aF[3] = QLDA(3, 0, c);
    if (t == 0) { QSTAGE(1, 1, 1); QSTAGE(3, 1, 1); }
    BARRIER();
    __builtin_amdgcn_s_setprio(1);
    mfma16<0>(aF, bF, acc);
    __builtin_amdgcn_s_setprio(0);
    __builtin_amdgcn_sched_barrier(0);
    BARRIER();
    aF[0] = QLDA(4, 0, c); aF[1] = QLDA(5, 0, c);
    aF[2] = QLDA(6, 0, c); aF[3] = QLDA(7, 0, c);
    BARRIER();
    __builtin_amdgcn_s_setprio(1);
    mfma16<4>(aF, bF, acc);
    __builtin_amdgcn_s_setprio(0);
    __builtin_amdgcn_sched_barrier(0);
    BARRIER();
    bF[0] = QLDB(0, 1, c); bF[1] = QLDB(1, 1, c);
    bF[2] = QLDB(2, 1, c); bF[3] = QLDB(3, 1, c);
    aF[0] = QLDA(0, 1, c); aF[1] = QLDA(1, 1, c);
    aF[2] = QLDA(2, 1, c); aF[3] = QLDA(3, 1, c);
    BARRIER();
    __builtin_amdgcn_s_setprio(1);
    mfma16<0>(aF, bF, acc);
    __builtin_amdgcn_s_setprio(0);
    __builtin_amdgcn_sched_barrier(0);
    BARRIER();
    aF[0] = QLDA(4, 1, c); aF[1] = QLDA(5, 1, c);
    aF[2] = QLDA(6, 1, c); aF[3] = QLDA(7, 1, c);
    BARRIER();
    __builtin_amdgcn_s_setprio(1);
    mfma16<4>(aF, bF, acc);
    __builtin_amdgcn_s_setprio(0);
    __builtin_amdgcn_sched_barrier(0);
    BARRIER();
  }

  const float scale = 0.08838834764831845f;
  const int r0 = lq * 4;
#pragma unroll
  for (int mi = 0; mi < 8; ++mi)
#pragma unroll
    for (int ni = 0; ni < 4; ++ni)
#pragma unroll
      for (int r = 0; r < 4; ++r) {
        const int gm = m0 + wm * 128 + mi * 16 + r0 + r;
        const int gn = n0 + wn * 64 + ni * 16 + fr;
        outp[(size_t)gm * 1024 + gn] = f2h(acc[mi][ni][r] * scale);
      }
#undef QSTAGE
#undef QLDA
#undef QLDB
}

// ---------------------------------------------------------------------------
// Row softmax, in place. Read-trim to 64-col granularity; zero-fill up to
// the 256-col boundary that PV reads.
// ---------------------------------------------------------------------------
__global__ __launch_bounds__(256) void softmax_rows(unsigned short* __restrict__ s) {
  const int row = blockIdx.x, tid = threadIdx.x;
  const int lane = tid & 63, wave = tid >> 6;
  const int qv = row & 1023;
  const int nact64 = ((qv >> 6) + 1) << 6;
  const int nact256 = ((qv >> 8) + 1) << 8;
  unsigned short* r = s + (size_t)row * 1024;
  const int col = tid * 4;
  const bool act = (col < nact64);
  float v[4];
  if (act) {
    u16x4 raw = *reinterpret_cast<const u16x4*>(r + col);
#pragma unroll
    for (int j = 0; j < 4; ++j)
      v[j] = (col + j <= qv) ? h2f(((unsigned short*)&raw)[j]) : -1e30f;
  } else {
#pragma unroll
    for (int j = 0; j < 4; ++j) v[j] = -1e30f;
  }
  float mx = fmaxf(fmaxf(v[0], v[1]), fmaxf(v[2], v[3]));
#pragma unroll
  for (int off = 1; off < 64; off <<= 1) mx = fmaxf(mx, __shfl_xor(mx, off, 64));
  __shared__ float redm[4], reds[4];
  if (lane == 0) redm[wave] = mx;
  __syncthreads();
  const float M = fmaxf(fmaxf(redm[0], redm[1]), fmaxf(redm[2], redm[3]));
  float e[4], ts = 0.f;
#pragma unroll
  for (int j = 0; j < 4; ++j) {
    e[j] = (act && col + j <= qv) ? __expf(v[j] - M) : 0.f;
    ts += e[j];
  }
#pragma unroll
  for (int off = 1; off < 64; off <<= 1) ts += __shfl_xor(ts, off, 64);
  if (lane == 0) reds[wave] = ts;
  __syncthreads();
  const float inv = 1.f / (reds[0] + reds[1] + reds[2] + reds[3]);
  if (act) {
    u16x4 o;
    o.x = f2bf(e[0] * inv); o.y = f2bf(e[1] * inv);
    o.z = f2bf(e[2] * inv); o.w = f2bf(e[3] * inv);
    *reinterpret_cast<u16x4*>(r + col) = o;
  } else if (col < nact256) {
    u16x4 o; o.x = 0; o.y = 0; o.z = 0; o.w = 0;
    *reinterpret_cast<u16x4*>(r + col) = o;
  }
}

// ---------------------------------------------------------------------------
// PV GEMM: BM=256, BN=64, BK=64, 4 waves. NT = by*4+4. Grid (2,4,32).
// ---------------------------------------------------------------------------
__global__ __launch_bounds__(256, 2) void gemm_pv(
    const unsigned short* __restrict__ p, const unsigned short* __restrict__ vt,
    unsigned short* __restrict__ ao) {
  __shared__ unsigned short lds[40960];
  const int tid = threadIdx.x, lane = tid & 63, wave = tid >> 6;
  const int fr = lane & 15, lq = lane >> 4;
  const int bxn = blockIdx.x, by = blockIdx.y, z = blockIdx.z;
  const int b = z >> 4, h = z & 15, kvh = h >> 2;
  const int m0p = by * 256, n0 = bxn * 64;
  const int NT = by * 4 + 4;

  const unsigned short* A = p + (size_t)z * 1048576 + (size_t)m0p * 1024;
  const unsigned short* W =
      vt + ((size_t)(b * 4 + kvh) * 128 + n0) * 1024;

#define PVSTAGE(tt_, c_)                                                      \
  do {                                                                        \
    _Pragma("unroll")                                                         \
    for (int j = 0; j < 8; ++j) {                                             \
      const int u = wave * 512 + j * 64 + lane;                               \
      const int rw = u >> 3;                                                  \
      gload_lds16(A + (size_t)rw * 1024 + (((u & 7) ^ (rw & 7)) << 3) +       \
                      (size_t)(tt_)*64,                                       \
                  &lds[(c_)*20480 + wave * 4096 + j * 512]);                  \
    }                                                                         \
    _Pragma("unroll")                                                         \
    for (int j = 0; j < 2; ++j) {                                             \
      const int u = wave * 128 + j * 64 + lane;                               \
      const int rw = u >> 3;                                                  \
      gload_lds16(W + (size_t)rw * 1024 + (((u & 7) ^ (rw & 7)) << 3) +       \
                      (size_t)(tt_)*64,                                       \
                  &lds[(c_)*20480 + 16384 + wave * 1024 + j * 512]);          \
    }                                                                         \
  } while (0)

  const int e0 = lq ^ (fr & 7);
#define PVLDA(mi_, ks_, c_)                                                   \
  (*reinterpret_cast<const bf16x8*>(                                          \
      &lds[(c_)*20480 + (wave * 64 + (mi_)*16 + fr) * 64 +                    \
           ((e0 ^ ((ks_)*4)) << 3)]))
#define PVLDB(ni_, ks_, c_)                                                   \
  (*reinterpret_cast<const bf16x8*>(                                          \
      &lds[(c_)*20480 + 16384 + ((ni_)*16 + fr) * 64 +                        \
           ((e0 ^ ((ks_)*4)) << 3)]))

  f32x4 acc[4][4] = {};
  bf16x8 aF[4], bF[4];

  PVSTAGE(0, 0);

  for (int t = 0; t < NT; ++t) {
    const int c = t & 1;
    if (t + 1 < NT) {
      PVSTAGE(t + 1, c ^ 1);
      asm volatile("s_waitcnt vmcnt(10)" ::: "memory");
    } else {
      asm volatile("s_waitcnt vmcnt(0)" ::: "memory");
    }
    BARRIER();
#pragma unroll
    for (int ks = 0; ks < 2; ++ks) {
      bF[0] = PVLDB(0, ks, c); bF[1] = PVLDB(1, ks, c);
      bF[2] = PVLDB(2, ks, c); bF[3] = PVLDB(3, ks, c);
      aF[0] = PVLDA(0, ks, c); aF[1] = PVLDA(1, ks, c);
      aF[2] = PVLDA(2, ks, c); aF[3] = PVLDA(3, ks, c);
      BARRIER();
      __builtin_amdgcn_s_setprio(1);
#pragma unroll
      for (int ni = 0; ni < 4; ++ni)
#pragma unroll
        for (int mi = 0; mi < 4; ++mi)
          acc[mi][ni] = __builtin_amdgcn_mfma_f32_16x16x32_bf16(
              aF[mi], bF[ni], acc[mi][ni], 0, 0, 0);
      __builtin_amdgcn_s_setprio(0);
      __builtin_amdgcn_sched_barrier(0);
      BARRIER();
    }
  }

  const int r0 = lq * 4;
#pragma unroll
  for (int mi = 0; mi < 4; ++mi)
#pragma unroll
    for (int ni = 0; ni < 4; ++ni)
#pragma unroll
      for (int r = 0; r < 4; ++r) {
        const int gm = m0p + wave * 64 + mi * 16 + r0 + r;
        const int gn = n0 + ni * 16 + fr;
        ao[(size_t)(b * 1024 + gm) * HIDDIM + h * HDIM + gn] =
            f2bf(acc[mi][ni][r]);
      }
#undef PVSTAGE
#undef PVLDA
#undef PVLDB
}

// ---------------------------------------------------------------------------
// QKV split-K2 reduce (bf16 partials) + bias + RoPE + V-transpose.
// ---------------------------------------------------------------------------
__global__ __launch_bounds__(256) void reduce_qkv(
    const unsigned short* __restrict__ p, const float* __restrict__ qb,
    const float* __restrict__ kb, const float* __restrict__ vb,
    const float* __restrict__ cosb, const float* __restrict__ sinb,
    unsigned short* __restrict__ qo, unsigned short* __restrict__ ko,
    unsigned short* __restrict__ vto) {
  const int i = blockIdx.x * 256 + threadIdx.x;
  const int row = i / 768, c4 = (i - row * 768) * 4;
  const unsigned short* p0 = p + (size_t)row * 3072;
  const unsigned short* p1 = p + 6291456 + (size_t)row * 3072;
  const u16x4 a0 = *reinterpret_cast<const u16x4*>(p0 + c4);
  const u16x4 a1 = *reinterpret_cast<const u16x4*>(p1 + c4);
  f32x4 s;
  s.x = bf2f(a0.x) + bf2f(a1.x); s.y = bf2f(a0.y) + bf2f(a1.y);
  s.z = bf2f(a0.z) + bf2f(a1.z); s.w = bf2f(a0.w) + bf2f(a1.w);
  if (c4 < 2560) {
    const float* bias; unsigned short* out; int d, ldo;
    if (c4 < 2048) { bias = qb; out = qo; d = c4;        ldo = HIDDIM; }
    else           { bias = kb; out = ko; d = c4 - 2048; ldo = KVDIM; }
    const int dd = d & 127;
    const bool lohalf = (dd < 64);
    const int pc = lohalf ? c4 + 64 : c4 - 64;
    const int pd = lohalf ? d + 64 : d - 64;
    const u16x4 b0 = *reinterpret_cast<const u16x4*>(p0 + pc);
    const u16x4 b1 = *reinterpret_cast<const u16x4*>(p1 + pc);
    f32x4 sp;
    sp.x = bf2f(b0.x) + bf2f(b1.x); sp.y = bf2f(b0.y) + bf2f(b1.y);
    sp.z = bf2f(b0.z) + bf2f(b1.z); sp.w = bf2f(b0.w) + bf2f(b1.w);
    const f32x4 bv = *reinterpret_cast<const f32x4*>(bias + d);
    const f32x4 bp = *reinterpret_cast<const f32x4*>(bias + pd);
    const f32x4 cv = *reinterpret_cast<const f32x4*>(cosb + (size_t)row * 128 + dd);
    const f32x4 sv = *reinterpret_cast<const f32x4*>(sinb + (size_t)row * 128 + dd);
    const f32x4 xv = s + bv, pv = sp + bp;
    f32x4 o;
    if (lohalf) o = xv * cv - pv * sv;
    else        o = xv * cv + pv * sv;
    u16x4 ob;
    ob.x = f2bf(o.x); ob.y = f2bf(o.y); ob.z = f2bf(o.z); ob.w = f2bf(o.w);
    *reinterpret_cast<u16x4*>(out + (size_t)row * ldo + d) = ob;
  } else {
    const int d = c4 - 2560;
    const int kvh = d >> 7, dd = d & 127;
    const int b = row >> 10, t = row & 1023;
    const f32x4 bv = *reinterpret_cast<const f32x4*>(vb + d);
    const f32x4 o = s + bv;
    unsigned short* vr =
        vto + ((size_t)(b * 4 + kvh) * 128 + dd) * 1024 + t;
    vr[0] = f2bf(o.x); vr[1024] = f2bf(o.y);
    vr[2048] = f2bf(o.z); vr[3072] = f2bf(o.w);
  }
}

// ---------------------------------------------------------------------------
extern "C" void kernel_launch(void* const* d_in, const int* in_sizes, int n_in,
                              void* d_out, int out_size, void* d_ws,
                              size_t ws_size, hipStream_t stream) {
  (void)in_sizes; (void)n_in; (void)out_size; (void)ws_size;
  const float* hidden = (const float*)d_in[0];
  const float* cosb  = (const float*)d_in[1];
  const float* sinb  = (const float*)d_in[2];
  const float* qw    = (const float*)d_in[3];
  const float* qbias = (const float*)d_in[4];
  const float* kw    = (const float*)d_in[5];
  const float* kbias = (const float*)d_in[6];
  const float* vw    = (const float*)d_in[7];
  const float* vbias = (const float*)d_in[8];
  const float* ow    = (const float*)d_in[9];
  const float* gw    = (const float*)d_in[10];
  const float* uw    = (const float*)d_in[11];
  const float* dw    = (const float*)d_in[12];
  const float* ln1   = (const float*)d_in[13];
  const float* ln2   = (const float*)d_in[14];
  const float* normw = (const float*)d_in[15];

  char* ws = (char*)d_ws;
  float* x               = (float*)ws;                          // 0      16.8M
  unsigned short* hbuf   = (unsigned short*)(ws + 16777216);    // 16.8M   8.4M
  unsigned short* qbuf   = (unsigned short*)(ws + 25165824);    // 25.2M   8.4M
  unsigned short* kbuf   = (unsigned short*)(ws + 33554432);    // 33.6M   2.1M
  unsigned short* vtbuf  = (unsigned short*)(ws + 35651584);    // 35.7M   2.1M
  unsigned short* aobuf  = (unsigned short*)(ws + 39845888);    // 39.8M   8.4M
  unsigned short* actbuf = (unsigned short*)(ws + 71303168);    // 71.3M  23.1M
  unsigned short* wcvt   = (unsigned short*)(ws + 94371840);    // 94.4M  23.1M
  // Overlays (dead regions at time-of-use, stream-serialized):
  unsigned short* pbQKV = (unsigned short*)(ws + 37748736);  // 2x12.6MB
  unsigned short* sbuf  = (unsigned short*)(ws + 48234496);  // 67MB; tail
                                                             // aliases wcvt!
  unsigned short* pbO   = (unsigned short*)(ws + 48234496);  // 4x8.4MB
  unsigned short* wgu   = (unsigned short*)(ws + 25165824);  // 46.1MB
  unsigned short* pbD   = (unsigned short*)(ws + 25165824);  // 4x8.4MB

  unsigned short* wq16 = wcvt;
  unsigned short* wk16 = wcvt + 4194304;
  unsigned short* wv16 = wcvt + 5242880;
  unsigned short* ow16 = hbuf;   // O weights live in the (dead) hbuf region
                                 // during attention — NOT wcvt (sbuf alias).

  hipMemcpyAsync(x, hidden, (size_t)NTOK * HIDDIM * 4,
                 hipMemcpyDeviceToDevice, stream);
  rmsnorm_kernel<0><<<NTOK, 256, 0, stream>>>(x, ln1, hbuf);

  for (int l = 0; l < 4; ++l) {
    const float* qw_l = qw + (size_t)l * 2048 * 2048;
    const float* qb_l = qbias + (size_t)l * 2048;
    const float* kw_l = kw + (size_t)l * 512 * 2048;
    const float* kb_l = kbias + (size_t)l * 512;
    const float* vw_l = vw + (size_t)l * 512 * 2048;
    const float* vb_l = vbias + (size_t)l * 512;
    const float* ow_l = ow + (size_t)l * 2048 * 2048;
    const float* gw_l = gw + (size_t)l * 5632 * 2048;
    const float* uw_l = uw + (size_t)l * 5632 * 2048;
    const float* dw_l = dw + (size_t)l * 2048 * 5632;

    cvt_kernel<<<2048, 256, 0, stream>>>(qw_l, wq16, 524288);
    cvt_kernel<<<512, 256, 0, stream>>>(kw_l, wk16, 131072);
    cvt_kernel<<<512, 256, 0, stream>>>(vw_l, wv16, 131072);
    // fused QKV: [2048,2048] x [3072,2048]^T, split-K2 (sub-K=32: 64 subtiles)
    gemm16w<<<dim3(12, 8, 2), 1024, 0, stream>>>(
        hbuf, wcvt, pbQKV, 2048, 3072, 32, 64, (size_t)6291456);
    reduce_qkv<<<6144, 256, 0, stream>>>(pbQKV, qb_l, kb_l, vb_l, cosb, sinb,
                                         qbuf, kbuf, vtbuf);

    // attention; gemm_qk's causal-dead blocks convert the O weights into
    // ow16 = hbuf (dead: QKV GEMM consumed it, rewritten only after O-proj).
    gemm_qk<<<dim3(4, 4, 32), 512, 0, stream>>>(qbuf, kbuf, sbuf, ow_l, ow16);
    softmax_rows<<<32768, 256, 0, stream>>>(sbuf);
    gemm_pv<<<dim3(2, 4, 32), 256, 0, stream>>>(sbuf, vtbuf, aobuf);

    // O-proj: split-K4 (reads ow16 = hbuf region, then reduce_rms rewrites it)
    gemm16w<<<dim3(8, 8, 4), 1024, 0, stream>>>(
        aobuf, ow16, pbO, 2048, 2048, 16, 64, (size_t)4194304);
    reduce_rms<4, 0><<<NTOK, 256, 0, stream>>>(x, pbO, (size_t)4194304,
                                               ln2 + l * 2048, hbuf);

    // gate+up fused (8-wave BK=64 8-phase); z=1 aux plane converts the
    // down weights into wcvt (sbuf — the alias — is dead by now).
    cvt_gu<<<11264, 256, 0, stream>>>(gw_l, uw_l, wgu);
    gemm_gu<<<dim3(44, 8, 2), 512, 0, stream>>>(hbuf, wgu, actbuf, dw_l, wcvt);

    // down: split-K4 (K=5632 -> 176 subtiles -> 44/split)
    gemm16w<<<dim3(8, 8, 4), 1024, 0, stream>>>(
        actbuf, wcvt, pbD, 5632, 2048, 44, 176, (size_t)4194304);
    if (l < 3) {
      reduce_rms<4, 0><<<NTOK, 256, 0, stream>>>(
          x, pbD, (size_t)4194304, ln1 + (l + 1) * 2048, hbuf);
    } else {
      reduce_rms<4, 1><<<NTOK, 256, 0, stream>>>(x, pbD, (size_t)4194304,
                                                 normw, d_out);
    }
  }
}